// Round 6
// baseline (822.674 us; speedup 1.0000x reference)
//
#include <hip/hip_runtime.h>
#include <math.h>

#define NB 32
#define NN 3136
#define CD 320
#define NH 5
#define CN 400
#define NKEY 196
#define DQ 80
#define DV 64
#define SCALE_F 0.11180339887498949f

typedef __bf16 bf16x8 __attribute__((ext_vector_type(8)));
typedef float f32x4 __attribute__((ext_vector_type(4)));
typedef unsigned short u16;
typedef unsigned int u32;

__device__ __forceinline__ u16 f2bf(float f) {
  u32 u = __float_as_uint(f);
  u += 0x7fffu + ((u >> 16) & 1u);  // round-to-nearest-even
  return (u16)(u >> 16);
}

__device__ __forceinline__ uint2 pack4(float a, float b, float c, float d) {
  return make_uint2((u32)f2bf(a) | ((u32)f2bf(b) << 16),
                    (u32)f2bf(c) | ((u32)f2bf(d) << 16));
}

// ---------------------------------------------------------------------------
// Prep: qwT bf16 [400][320]; pwT bf16 [320][320]; kvwT bf16 [720][416]
// (rows 0..399 = k_w^T, rows 400..719 = v_w^T, cols 400..415 zero);
// pwb bf16 [400][320] = pw_w cast (native out-major layout).
// ---------------------------------------------------------------------------
__global__ void k_prep(const float* __restrict__ q_w,
                       const float* __restrict__ proj_w,
                       const float* __restrict__ k_w,
                       const float* __restrict__ v_w,
                       const float* __restrict__ pw_w, u16* __restrict__ qwT,
                       u16* __restrict__ pwT, u16* __restrict__ kvwT,
                       u16* __restrict__ pwb) {
  const int i0 = blockIdx.x * 256 + threadIdx.x;
  const int stride = gridDim.x * 256;
  for (int idx = i0; idx < 400 * 320; idx += stride) {
    const int o = idx / 320, c = idx - o * 320;
    qwT[idx] = f2bf(q_w[(size_t)c * 400 + o]);
  }
  for (int idx = i0; idx < 320 * 320; idx += stride) {
    const int o = idx / 320, c = idx - o * 320;
    pwT[idx] = f2bf(proj_w[(size_t)c * 320 + o]);
  }
  for (int idx = i0; idx < 400 * 320; idx += stride) {
    pwb[idx] = f2bf(pw_w[idx]);
  }
  for (int idx = i0; idx < 720 * 416; idx += stride) {
    const int o = idx / 416, c = idx - o * 416;
    float v = 0.f;
    if (c < 400) v = (o < 400) ? k_w[(size_t)c * 400 + o] : v_w[(size_t)c * 320 + (o - 400)];
    kvwT[idx] = f2bf(v);
  }
}

// ---------------------------------------------------------------------------
// Kernel 1a: depthwise 4x4/s4 conv, pure streaming; each x element is read by
// exactly one thread, so we ALSO emit the bf16 cast of x:
//   xbf  = bf16 x, overlaid in the qb region (row stride 400, cols 0..319)
//   dwc16 = bf16 dw-conv output, overlaid in the xs region (stride 416)
// grid 1960 (= 6272*80/256), thread = 4 channels of one output pixel.
// ---------------------------------------------------------------------------
__global__ __launch_bounds__(256) void k_dw(const float* __restrict__ x,
                                            const float* __restrict__ dw_w,
                                            const float* __restrict__ dw_b,
                                            u16* __restrict__ dwc16,
                                            u16* __restrict__ xbf) {
  const int idx = blockIdx.x * 256 + threadIdx.x;  // 6272*80
  const int row = idx / 80, c4 = (idx - row * 80) * 4;
  const int b = row / 196, pl = row - b * 196;
  const int oh = pl / 14, ow = pl - oh * 14;
  const size_t pix0 = (size_t)b * NN + (size_t)(oh * 4) * 56 + ow * 4;
  const float* xb = x + pix0 * CD + c4;

  float w[4][16];
#pragma unroll
  for (int k = 0; k < 4; k++)
#pragma unroll
    for (int j4 = 0; j4 < 4; j4++)
      *(float4*)&w[k][j4 * 4] = *(const float4*)(dw_w + (c4 + k) * 16 + j4 * 4);

  float a0 = dw_b[c4], a1 = dw_b[c4 + 1], a2 = dw_b[c4 + 2], a3 = dw_b[c4 + 3];
#pragma unroll
  for (int i = 0; i < 4; i++)
#pragma unroll
    for (int j = 0; j < 4; j++) {
      const float4 xv = *(const float4*)(xb + (size_t)(i * 56 + j) * CD);
      const int t = i * 4 + j;
      a0 += xv.x * w[0][t];
      a1 += xv.y * w[1][t];
      a2 += xv.z * w[2][t];
      a3 += xv.w * w[3][t];
      *(uint2*)(xbf + (pix0 + i * 56 + j) * CN + c4) =
          pack4(xv.x, xv.y, xv.z, xv.w);
    }
  *(uint2*)(dwc16 + (size_t)row * 416 + c4) = pack4(a0, a1, a2, a3);
}

// ---------------------------------------------------------------------------
// Kernel 1b: 1x1 conv as MFMA GEMM (OPERAND-SWAPPED: A=weights, B=dwc rows ->
// C^T in regs). +bias, LN, GELU in registers. One wave per 16 rows;
// grid 392 x 64 threads.
// In-place in the xs region: reads dwc16 (cols 0..319), writes cols 0..399.
// ---------------------------------------------------------------------------
__global__ __launch_bounds__(64) void k_pwln(u16* xs,
                                             const u16* __restrict__ pwb,
                                             const float* __restrict__ pw_b,
                                             const float* __restrict__ ln_g,
                                             const float* __restrict__ ln_b) {
  const int lane = threadIdx.x & 63;
  const int quad = lane >> 4, l15 = lane & 15;
  const int row0 = blockIdx.x * 16;
  const f32x4 fz = {0.f, 0.f, 0.f, 0.f};

  bf16x8 Bfr[10];
  {
    const u16* xr = xs + (size_t)(row0 + l15) * 416;
#pragma unroll
    for (int ks = 0; ks < 10; ks++)
      Bfr[ks] = *(const bf16x8*)(xr + ks * 32 + quad * 8);
  }
  f32x4 acc[25];
#pragma unroll
  for (int n = 0; n < 25; n++) acc[n] = fz;
#pragma unroll 1
  for (int n = 0; n < 25; n++) {
    const u16* wr = pwb + (size_t)(n * 16 + l15) * CD;
#pragma unroll
    for (int ks = 0; ks < 10; ks++) {
      const bf16x8 A = *(const bf16x8*)(wr + ks * 32 + quad * 8);
      acc[n] = __builtin_amdgcn_mfma_f32_16x16x32_bf16(A, Bfr[ks], acc[n], 0, 0, 0);
    }
    const float4 pb = *(const float4*)(pw_b + n * 16 + quad * 4);
    acc[n][0] += pb.x; acc[n][1] += pb.y; acc[n][2] += pb.z; acc[n][3] += pb.w;
  }
  // LN stats for row l15 (each lane holds 100 of the 400 channels)
  float s = 0.f, ss = 0.f;
#pragma unroll
  for (int n = 0; n < 25; n++)
#pragma unroll
    for (int r = 0; r < 4; r++) {
      s += acc[n][r];
      ss += acc[n][r] * acc[n][r];
    }
  s += __shfl_xor(s, 16); ss += __shfl_xor(ss, 16);
  s += __shfl_xor(s, 32); ss += __shfl_xor(ss, 32);
  const float mu = s * (1.f / 400.f);
  const float var = ss * (1.f / 400.f) - mu * mu;
  const float rstd = rsqrtf(var + 1e-5f);

  u16* orow = xs + (size_t)(row0 + l15) * 416;
#pragma unroll 1
  for (int n = 0; n < 25; n++) {
    const float4 g = *(const float4*)(ln_g + n * 16 + quad * 4);
    const float4 bb = *(const float4*)(ln_b + n * 16 + quad * 4);
    float ge[4];
#pragma unroll
    for (int r = 0; r < 4; r++) {
      const float gg = (&g.x)[r], bv = (&bb.x)[r];
      const float v = (acc[n][r] - mu) * rstd * gg + bv;
      ge[r] = 0.5f * v * (1.f + erff(v * 0.70710678118654752f));
    }
    *(uint2*)(orow + n * 16 + quad * 4) = pack4(ge[0], ge[1], ge[2], ge[3]);
  }
  *(uint2*)(orow + 400 + quad * 4) = make_uint2(0, 0);
}

// ---------------------------------------------------------------------------
// Kernel 2 (MFMA, barrier-free): [6272][416]bf16 @ kvwT^T -> kb [6272][400],
// vt [32][320][224] (v transposed, keys 196..223 left as poison — harmless).
// grid (392, 3) x 64 threads. wave = 16 rows, N-chunk = 15 tiles of 16.
// ---------------------------------------------------------------------------
__global__ __launch_bounds__(64) void k_kv(const u16* __restrict__ xs,
                                           const u16* __restrict__ kvwT,
                                           u16* __restrict__ kb,
                                           u16* __restrict__ vt) {
  const int lane = threadIdx.x & 63;
  const int quad = lane >> 4, l15 = lane & 15;
  const int mt = blockIdx.x;  // 0..391
  const f32x4 fz = {0.f, 0.f, 0.f, 0.f};

  bf16x8 A[13];
  {
    const u16* xr = xs + (size_t)(mt * 16 + l15) * 416;
#pragma unroll
    for (int ks = 0; ks < 13; ks++)
      A[ks] = *(const bf16x8*)(xr + ks * 32 + quad * 8);
  }
#pragma unroll 1
  for (int n = 0; n < 15; n++) {
    const int nt = blockIdx.y * 15 + n;
    f32x4 acc = fz;
    const u16* wr = kvwT + (size_t)(nt * 16 + l15) * 416;
#pragma unroll
    for (int ks = 0; ks < 13; ks++) {
      const bf16x8 B = *(const bf16x8*)(wr + ks * 32 + quad * 8);
      acc = __builtin_amdgcn_mfma_f32_16x16x32_bf16(A[ks], B, acc, 0, 0, 0);
    }
    const int col = nt * 16 + l15;
    if (col < 400) {
#pragma unroll
      for (int r = 0; r < 4; r++)
        kb[(size_t)(mt * 16 + quad * 4 + r) * 400 + col] = f2bf(acc[r]);
    } else {
      const int vo = col - 400;
#pragma unroll
      for (int r = 0; r < 4; r++) {
        const int row = mt * 16 + quad * 4 + r;
        const int bb = row / 196, key = row - bb * 196;
        vt[((size_t)(bb * 320 + vo)) * 224 + key] = f2bf(acc[r]);
      }
    }
  }
}

// ---------------------------------------------------------------------------
// Kernel 3 (MFMA, LDS/barrier-free, OPERAND-SWAPPED, IN-PLACE):
// qb = x @ q_w. Wave = 16 rows (was 32): 6272 waves vs 3136 — k_q was
// latency-bound at 27% occupancy purely from wave-count (3136/8192 slots).
// Reads xbf (bf16 x overlay, qb cols 0..319) fully to regs, then writes
// qb rows cols 0..399 (same-wave ordering -> in-place safe).
// grid 1568: 4 waves x 16 rows.
// ---------------------------------------------------------------------------
__global__ __launch_bounds__(256) void k_q(u16* qb,
                                           const u16* __restrict__ qwT) {
  const int tid = threadIdx.x, lane = tid & 63, wv = tid >> 6;
  const int quad = lane >> 4, l15 = lane & 15;
  const int r0 = (blockIdx.x * 4 + wv) * 16;
  const f32x4 fz = {0.f, 0.f, 0.f, 0.f};

  bf16x8 Bfr[10];
  {
    const u16* xr = qb + (size_t)(r0 + l15) * CN;  // xbf overlay
#pragma unroll
    for (int ks = 0; ks < 10; ks++)
      Bfr[ks] = *(const bf16x8*)(xr + ks * 32 + quad * 8);
  }
#pragma unroll 1
  for (int n = 0; n < 25; n++) {
    f32x4 acc = fz;
    const u16* wr = qwT + (size_t)(n * 16 + l15) * CD;
#pragma unroll
    for (int ks = 0; ks < 10; ks++) {
      const bf16x8 A = *(const bf16x8*)(wr + ks * 32 + quad * 8);
      acc = __builtin_amdgcn_mfma_f32_16x16x32_bf16(A, Bfr[ks], acc, 0, 0, 0);
    }
    *(uint2*)(qb + (size_t)(r0 + l15) * CN + n * 16 + quad * 4) =
        pack4(acc[0], acc[1], acc[2], acc[3]);
  }
}

// ---------------------------------------------------------------------------
// Kernel 4 v2: attention, OPERAND-SWAPPED, single barrier, P in registers.
// grid (5, 49, 32), 256 threads, LDS 31360 B -> 5 blocks/CU.
//   S^T = mfma(A=Ks, B=q): sacc[n][r] = S[key=n*16+quad*4+r][q-row l15].
//   Softmax per-lane (52 keys) + 2 cross-quad shuffles.
//   PV: O^T = mfma(A=V^T from vt, B=P^T built by 8 cross-quad shuffles/kk).
//   bf16 attn-out written in place into qb (own rows, cols h*80+0..63).
// Ks is exact [196][80]; n=12 A-rows clamp to row 195 (keys 196..207 are
// masked post-GEMM); ks=2 quad>=2 zeroed on BOTH operands (no overreads).
// ---------------------------------------------------------------------------
__global__ __launch_bounds__(256, 5) void k_attn(u16* __restrict__ qb,
                                                 const u16* __restrict__ kb,
                                                 const u16* __restrict__ vt) {
  const int h = blockIdx.x, qt = blockIdx.y, b = blockIdx.z;
  const int tid = threadIdx.x, lane = tid & 63, wv = tid >> 6;
  const int quad = lane >> 4, l15 = lane & 15;
  const int q0 = qt * 64, m0 = wv * 16;
  const f32x4 fz = {0.f, 0.f, 0.f, 0.f};

  __shared__ u16 Ks[196 * 80];  // 31360 B

  // stage K head-slice [196][80] -> Ks, linear (dest byte = idx*16)
  for (int idx = tid; idx < 1960; idx += 256) {
    const int key = idx / 10, g = idx - key * 10;
    *(uint4*)(Ks + idx * 8) =
        *(const uint4*)(kb + ((size_t)(b * NKEY + key)) * CN + h * DQ + g * 8);
  }
  __syncthreads();  // the only barrier

  // ---- S^T (13 key-tiles; K=80 exact, zero-padded to 96 on both operands)
  f32x4 sacc[13];
#pragma unroll
  for (int n = 0; n < 13; n++) sacc[n] = fz;
  {
    union { uint4 u; bf16x8 v; } z;
    z.u = make_uint4(0, 0, 0, 0);
    const u16* qr = qb + (size_t)(b * NN + q0 + m0 + l15) * CN + h * DQ;
    bf16x8 bq0 = *(const bf16x8*)(qr + quad * 8);
    bf16x8 bq1 = *(const bf16x8*)(qr + 32 + quad * 8);
    bf16x8 bq2 = (quad < 2) ? *(const bf16x8*)(qr + 64 + quad * 8) : z.v;
#pragma unroll
    for (int n = 0; n < 13; n++) {
      const int rr = n * 16 + l15;
      const u16* kr = Ks + ((rr > 195) ? 195 : rr) * 80;
      sacc[n] = __builtin_amdgcn_mfma_f32_16x16x32_bf16(
          *(const bf16x8*)(kr + quad * 8), bq0, sacc[n], 0, 0, 0);
      sacc[n] = __builtin_amdgcn_mfma_f32_16x16x32_bf16(
          *(const bf16x8*)(kr + 32 + quad * 8), bq1, sacc[n], 0, 0, 0);
      const bf16x8 ak2 = (quad < 2) ? *(const bf16x8*)(kr + 64 + quad * 8) : z.v;
      sacc[n] = __builtin_amdgcn_mfma_f32_16x16x32_bf16(ak2, bq2, sacc[n], 0, 0, 0);
    }
  }

  // ---- softmax: per-lane over 52 keys, cross-quad via shfl_xor 16/32
  u32 u[13][2];
  {
    float mx = -1e30f;
#pragma unroll
    for (int n = 0; n < 13; n++)
#pragma unroll
      for (int r = 0; r < 4; r++) {
        float s = sacc[n][r] * SCALE_F;
        if (n == 12 && quad != 0) s = -1e30f;  // keys 196..207
        sacc[n][r] = s;
        mx = fmaxf(mx, s);
      }
    mx = fmaxf(mx, __shfl_xor(mx, 16));
    mx = fmaxf(mx, __shfl_xor(mx, 32));
    float sum = 0.f;
#pragma unroll
    for (int n = 0; n < 13; n++)
#pragma unroll
      for (int r = 0; r < 4; r++) {
        const float e = __expf(sacc[n][r] - mx);
        sacc[n][r] = e;
        sum += e;
      }
    sum += __shfl_xor(sum, 16);
    sum += __shfl_xor(sum, 32);
    const float inv = 1.f / sum;
#pragma unroll
    for (int n = 0; n < 13; n++) {
      u[n][0] = (u32)f2bf(sacc[n][0] * inv) | ((u32)f2bf(sacc[n][1] * inv) << 16);
      u[n][1] = (u32)f2bf(sacc[n][2] * inv) | ((u32)f2bf(sacc[n][3] * inv) << 16);
    }
  }

  // ---- O^T = P^T-fed MFMA; B-frags built by cross-quad shuffles
  f32x4 oacc[4];
#pragma unroll
  for (int nn = 0; nn < 4; nn++) oacc[nn] = fz;
  {
    const u16* vbase = vt + (size_t)(b * 320 + h * DV) * 224;
    const int src0 = ((lane & 16) << 1) | l15;  // (quad&1)*32 + l15
    const int src1 = src0 + 16;
    const bool hi = (quad >= 2);
#pragma unroll
    for (int kk = 0; kk < 7; kk++) {
      union { bf16x8 v; u32 w[4]; } bp;
      const u32 a0 = (u32)__shfl((int)u[2 * kk][0], src0);
      const u32 a1 = (u32)__shfl((int)u[2 * kk][1], src0);
      const u32 a2 = (u32)__shfl((int)u[2 * kk][0], src1);
      const u32 a3 = (u32)__shfl((int)u[2 * kk][1], src1);
      u32 b0 = 0, b1 = 0, b2 = 0, b3 = 0;
      if (kk < 6) {
        b0 = (u32)__shfl((int)u[2 * kk + 1][0], src0);
        b1 = (u32)__shfl((int)u[2 * kk + 1][1], src0);
        b2 = (u32)__shfl((int)u[2 * kk + 1][0], src1);
        b3 = (u32)__shfl((int)u[2 * kk + 1][1], src1);
      }
      bp.w[0] = hi ? b0 : a0;
      bp.w[1] = hi ? b1 : a1;
      bp.w[2] = hi ? b2 : a2;
      bp.w[3] = hi ? b3 : a3;
#pragma unroll
      for (int nn = 0; nn < 4; nn++) {
        const bf16x8 A = *(const bf16x8*)(vbase + (size_t)(nn * 16 + l15) * 224 +
                                          kk * 32 + quad * 8);
        oacc[nn] = __builtin_amdgcn_mfma_f32_16x16x32_bf16(A, bp.v, oacc[nn], 0, 0, 0);
      }
    }
  }
  // ---- bf16 attn-out overlay into qb (own rows, cols h*80+0..63)
  u16* orow = qb + (size_t)(b * NN + q0 + m0 + l15) * CN + h * DQ;
#pragma unroll
  for (int nn = 0; nn < 4; nn++)
    *(uint2*)(orow + nn * 16 + quad * 4) =
        pack4(oacc[nn][0], oacc[nn][1], oacc[nn][2], oacc[nn][3]);
}

// ---------------------------------------------------------------------------
// Kernel 5 (LDS/barrier-free, OPERAND-SWAPPED): out = ao @ proj_w + proj_b.
// ao = bf16 attn-out overlaid in qb (row stride 400, head h at cols h*80..+63).
// Wave = 16 rows (was 32): 6272 waves for latency hiding, same as k_q.
// grid 1568; float4 stores (64B/row line-coalesced).
// ---------------------------------------------------------------------------
__global__ __launch_bounds__(256) void k_proj(const u16* __restrict__ ao,
                                              const u16* __restrict__ pwT,
                                              const float* __restrict__ proj_b,
                                              float* __restrict__ out) {
  const int tid = threadIdx.x, lane = tid & 63, wv = tid >> 6;
  const int quad = lane >> 4, l15 = lane & 15;
  const int r0 = (blockIdx.x * 4 + wv) * 16;
  const f32x4 fz = {0.f, 0.f, 0.f, 0.f};

  bf16x8 Bfr[10];
  {
    const u16* xr = ao + (size_t)(r0 + l15) * CN;
#pragma unroll
    for (int ks = 0; ks < 10; ks++)
      Bfr[ks] = *(const bf16x8*)(xr + (ks >> 1) * DQ + (ks & 1) * 32 + quad * 8);
  }
#pragma unroll 1
  for (int n = 0; n < 20; n++) {
    f32x4 acc = fz;
    const u16* wr = pwT + (size_t)(n * 16 + l15) * CD;
#pragma unroll
    for (int ks = 0; ks < 10; ks++) {
      const bf16x8 A = *(const bf16x8*)(wr + ks * 32 + quad * 8);
      acc = __builtin_amdgcn_mfma_f32_16x16x32_bf16(A, Bfr[ks], acc, 0, 0, 0);
    }
    const float4 pb = *(const float4*)(proj_b + n * 16 + quad * 4);
    float4 o;
    o.x = acc[0] + pb.x;
    o.y = acc[1] + pb.y;
    o.z = acc[2] + pb.z;
    o.w = acc[3] + pb.w;
    *(float4*)(out + (size_t)(r0 + l15) * CD + n * 16 + quad * 4) = o;
  }
}

// ---------------------------------------------------------------------------
extern "C" void kernel_launch(void* const* d_in, const int* in_sizes, int n_in,
                              void* d_out, int out_size, void* d_ws,
                              size_t ws_size, hipStream_t stream) {
  const float* x = (const float*)d_in[0];
  const float* dw_w = (const float*)d_in[3];
  const float* dw_b = (const float*)d_in[4];
  const float* pw_w = (const float*)d_in[5];
  const float* pw_b = (const float*)d_in[6];
  const float* ln_g = (const float*)d_in[7];
  const float* ln_b = (const float*)d_in[8];
  const float* q_w = (const float*)d_in[9];
  const float* k_w = (const float*)d_in[10];
  const float* v_w = (const float*)d_in[11];
  const float* proj_w = (const float*)d_in[12];
  const float* proj_b = (const float*)d_in[13];
  float* out = (float*)d_out;

  u16* w = (u16*)d_ws;
  u16* xs16 = w;                    // [6272][416]       = 2,609,152  (hosts dwc16 overlay)
  u16* kb16 = xs16 + 2609152;       // [6272][400]       = 2,508,800
  u16* vt16 = kb16 + 2508800;       // [32*320][224]     = 2,293,760
  u16* qb16 = vt16 + 2293760;       // [100352][400]+64  = 40,140,864 (hosts xbf + ao overlays)
  u16* qwT = qb16 + 40140864;       // [400][320]        = 128,000
  u16* pwT = qwT + 128000;          // [320][320]        = 102,400
  u16* kvwT = pwT + 102400;         // [720][416]        = 299,520
  u16* pwb = kvwT + 299520;         // [400][320]        = 128,000
                                    // total ~96.5 MB

  k_prep<<<512, 256, 0, stream>>>(q_w, proj_w, k_w, v_w, pw_w, qwT, pwT, kvwT,
                                  pwb);
  k_dw<<<1960, 256, 0, stream>>>(x, dw_w, dw_b, xs16 /*dwc16 overlay*/,
                                 qb16 /*xbf overlay*/);
  k_pwln<<<392, 64, 0, stream>>>(xs16, pwb, pw_b, ln_g, ln_b);
  k_kv<<<dim3(392, 3), 64, 0, stream>>>(xs16, kvwT, kb16, vt16);
  k_q<<<1568, 256, 0, stream>>>(qb16, qwT);
  k_attn<<<dim3(NH, 49, NB), 256, 0, stream>>>(qb16, kb16, vt16);
  k_proj<<<1568, 256, 0, stream>>>(qb16, pwT, proj_b, out);
}

// Round 7
// 584.864 us; speedup vs baseline: 1.4066x; 1.4066x over previous
//
#include <hip/hip_runtime.h>
#include <math.h>

#define NB 32
#define NN 3136
#define CD 320
#define NH 5
#define CN 400
#define NKEY 196
#define DQ 80
#define DV 64
#define SCALE_F 0.11180339887498949f

typedef __bf16 bf16x8 __attribute__((ext_vector_type(8)));
typedef float f32x4 __attribute__((ext_vector_type(4)));
typedef unsigned short u16;
typedef unsigned int u32;

__device__ __forceinline__ u16 f2bf(float f) {
  u32 u = __float_as_uint(f);
  u += 0x7fffu + ((u >> 16) & 1u);  // round-to-nearest-even
  return (u16)(u >> 16);
}

__device__ __forceinline__ uint2 pack4(float a, float b, float c, float d) {
  return make_uint2((u32)f2bf(a) | ((u32)f2bf(b) << 16),
                    (u32)f2bf(c) | ((u32)f2bf(d) << 16));
}

// ---------------------------------------------------------------------------
// Prep: qwT bf16 [400][320]; pwT bf16 [320][320]; kvwT bf16 [720][416]
// (rows 0..399 = k_w^T, rows 400..719 = v_w^T, cols 400..415 zero);
// pwb bf16 [400][320] = pw_w cast (native out-major layout).
// ---------------------------------------------------------------------------
__global__ void k_prep(const float* __restrict__ q_w,
                       const float* __restrict__ proj_w,
                       const float* __restrict__ k_w,
                       const float* __restrict__ v_w,
                       const float* __restrict__ pw_w, u16* __restrict__ qwT,
                       u16* __restrict__ pwT, u16* __restrict__ kvwT,
                       u16* __restrict__ pwb) {
  const int i0 = blockIdx.x * 256 + threadIdx.x;
  const int stride = gridDim.x * 256;
  for (int idx = i0; idx < 400 * 320; idx += stride) {
    const int o = idx / 320, c = idx - o * 320;
    qwT[idx] = f2bf(q_w[(size_t)c * 400 + o]);
  }
  for (int idx = i0; idx < 320 * 320; idx += stride) {
    const int o = idx / 320, c = idx - o * 320;
    pwT[idx] = f2bf(proj_w[(size_t)c * 320 + o]);
  }
  for (int idx = i0; idx < 400 * 320; idx += stride) {
    pwb[idx] = f2bf(pw_w[idx]);
  }
  for (int idx = i0; idx < 720 * 416; idx += stride) {
    const int o = idx / 416, c = idx - o * 416;
    float v = 0.f;
    if (c < 400) v = (o < 400) ? k_w[(size_t)c * 400 + o] : v_w[(size_t)c * 320 + (o - 400)];
    kvwT[idx] = f2bf(v);
  }
}

// ---------------------------------------------------------------------------
// Kernel 1a: depthwise 4x4/s4 conv, pure streaming; each x element is read by
// exactly one thread, so we ALSO emit the bf16 cast of x:
//   xbf  = bf16 x, overlaid in the qb region (row stride 400, cols 0..319)
//   dwc16 = bf16 dw-conv output, overlaid in the xs region (stride 416)
// grid 1960 (= 6272*80/256), thread = 4 channels of one output pixel.
// ---------------------------------------------------------------------------
__global__ __launch_bounds__(256) void k_dw(const float* __restrict__ x,
                                            const float* __restrict__ dw_w,
                                            const float* __restrict__ dw_b,
                                            u16* __restrict__ dwc16,
                                            u16* __restrict__ xbf) {
  const int idx = blockIdx.x * 256 + threadIdx.x;  // 6272*80
  const int row = idx / 80, c4 = (idx - row * 80) * 4;
  const int b = row / 196, pl = row - b * 196;
  const int oh = pl / 14, ow = pl - oh * 14;
  const size_t pix0 = (size_t)b * NN + (size_t)(oh * 4) * 56 + ow * 4;
  const float* xb = x + pix0 * CD + c4;

  float w[4][16];
#pragma unroll
  for (int k = 0; k < 4; k++)
#pragma unroll
    for (int j4 = 0; j4 < 4; j4++)
      *(float4*)&w[k][j4 * 4] = *(const float4*)(dw_w + (c4 + k) * 16 + j4 * 4);

  float a0 = dw_b[c4], a1 = dw_b[c4 + 1], a2 = dw_b[c4 + 2], a3 = dw_b[c4 + 3];
#pragma unroll
  for (int i = 0; i < 4; i++)
#pragma unroll
    for (int j = 0; j < 4; j++) {
      const float4 xv = *(const float4*)(xb + (size_t)(i * 56 + j) * CD);
      const int t = i * 4 + j;
      a0 += xv.x * w[0][t];
      a1 += xv.y * w[1][t];
      a2 += xv.z * w[2][t];
      a3 += xv.w * w[3][t];
      *(uint2*)(xbf + (pix0 + i * 56 + j) * CN + c4) =
          pack4(xv.x, xv.y, xv.z, xv.w);
    }
  *(uint2*)(dwc16 + (size_t)row * 416 + c4) = pack4(a0, a1, a2, a3);
}

// ---------------------------------------------------------------------------
// Kernel 1b: 1x1 conv as MFMA GEMM (OPERAND-SWAPPED: A=weights, B=dwc rows ->
// C^T in regs). +bias, LN, GELU in registers. One wave per 16 rows;
// grid 392 x 64 threads.
// In-place in the xs region: reads dwc16 (cols 0..319), writes cols 0..399.
// ---------------------------------------------------------------------------
__global__ __launch_bounds__(64) void k_pwln(u16* xs,
                                             const u16* __restrict__ pwb,
                                             const float* __restrict__ pw_b,
                                             const float* __restrict__ ln_g,
                                             const float* __restrict__ ln_b) {
  const int lane = threadIdx.x & 63;
  const int quad = lane >> 4, l15 = lane & 15;
  const int row0 = blockIdx.x * 16;
  const f32x4 fz = {0.f, 0.f, 0.f, 0.f};

  bf16x8 Bfr[10];
  {
    const u16* xr = xs + (size_t)(row0 + l15) * 416;
#pragma unroll
    for (int ks = 0; ks < 10; ks++)
      Bfr[ks] = *(const bf16x8*)(xr + ks * 32 + quad * 8);
  }
  f32x4 acc[25];
#pragma unroll
  for (int n = 0; n < 25; n++) acc[n] = fz;
#pragma unroll 1
  for (int n = 0; n < 25; n++) {
    const u16* wr = pwb + (size_t)(n * 16 + l15) * CD;
#pragma unroll
    for (int ks = 0; ks < 10; ks++) {
      const bf16x8 A = *(const bf16x8*)(wr + ks * 32 + quad * 8);
      acc[n] = __builtin_amdgcn_mfma_f32_16x16x32_bf16(A, Bfr[ks], acc[n], 0, 0, 0);
    }
    const float4 pb = *(const float4*)(pw_b + n * 16 + quad * 4);
    acc[n][0] += pb.x; acc[n][1] += pb.y; acc[n][2] += pb.z; acc[n][3] += pb.w;
  }
  // LN stats for row l15 (each lane holds 100 of the 400 channels)
  float s = 0.f, ss = 0.f;
#pragma unroll
  for (int n = 0; n < 25; n++)
#pragma unroll
    for (int r = 0; r < 4; r++) {
      s += acc[n][r];
      ss += acc[n][r] * acc[n][r];
    }
  s += __shfl_xor(s, 16); ss += __shfl_xor(ss, 16);
  s += __shfl_xor(s, 32); ss += __shfl_xor(ss, 32);
  const float mu = s * (1.f / 400.f);
  const float var = ss * (1.f / 400.f) - mu * mu;
  const float rstd = rsqrtf(var + 1e-5f);

  u16* orow = xs + (size_t)(row0 + l15) * 416;
#pragma unroll 1
  for (int n = 0; n < 25; n++) {
    const float4 g = *(const float4*)(ln_g + n * 16 + quad * 4);
    const float4 bb = *(const float4*)(ln_b + n * 16 + quad * 4);
    float ge[4];
#pragma unroll
    for (int r = 0; r < 4; r++) {
      const float gg = (&g.x)[r], bv = (&bb.x)[r];
      const float v = (acc[n][r] - mu) * rstd * gg + bv;
      ge[r] = 0.5f * v * (1.f + erff(v * 0.70710678118654752f));
    }
    *(uint2*)(orow + n * 16 + quad * 4) = pack4(ge[0], ge[1], ge[2], ge[3]);
  }
  *(uint2*)(orow + 400 + quad * 4) = make_uint2(0, 0);
}

// ---------------------------------------------------------------------------
// Kernel 2 (MFMA, barrier-free): [6272][416]bf16 @ kvwT^T -> kb [6272][400],
// vt [32][320][224] (v transposed, keys 196..223 left as poison — harmless).
// grid (392, 3) x 64 threads. wave = 16 rows, N-chunk = 15 tiles of 16.
// ---------------------------------------------------------------------------
__global__ __launch_bounds__(64) void k_kv(const u16* __restrict__ xs,
                                           const u16* __restrict__ kvwT,
                                           u16* __restrict__ kb,
                                           u16* __restrict__ vt) {
  const int lane = threadIdx.x & 63;
  const int quad = lane >> 4, l15 = lane & 15;
  const int mt = blockIdx.x;  // 0..391
  const f32x4 fz = {0.f, 0.f, 0.f, 0.f};

  bf16x8 A[13];
  {
    const u16* xr = xs + (size_t)(mt * 16 + l15) * 416;
#pragma unroll
    for (int ks = 0; ks < 13; ks++)
      A[ks] = *(const bf16x8*)(xr + ks * 32 + quad * 8);
  }
#pragma unroll 1
  for (int n = 0; n < 15; n++) {
    const int nt = blockIdx.y * 15 + n;
    f32x4 acc = fz;
    const u16* wr = kvwT + (size_t)(nt * 16 + l15) * 416;
#pragma unroll
    for (int ks = 0; ks < 13; ks++) {
      const bf16x8 B = *(const bf16x8*)(wr + ks * 32 + quad * 8);
      acc = __builtin_amdgcn_mfma_f32_16x16x32_bf16(A[ks], B, acc, 0, 0, 0);
    }
    const int col = nt * 16 + l15;
    if (col < 400) {
#pragma unroll
      for (int r = 0; r < 4; r++)
        kb[(size_t)(mt * 16 + quad * 4 + r) * 400 + col] = f2bf(acc[r]);
    } else {
      const int vo = col - 400;
#pragma unroll
      for (int r = 0; r < 4; r++) {
        const int row = mt * 16 + quad * 4 + r;
        const int bb = row / 196, key = row - bb * 196;
        vt[((size_t)(bb * 320 + vo)) * 224 + key] = f2bf(acc[r]);
      }
    }
  }
}

// ---------------------------------------------------------------------------
// Kernel 3 v3 (MFMA, OPERAND-SWAPPED, IN-PLACE, LDS weight staging):
// qb = x @ q_w. Block = 4 waves x 32 rows = 128 rows, grid 784.
// Round-6 lesson: every wave streaming the full 256KB qwT from L2 is the
// serializer (more occupancy made it WORSE). v3 stages each 16x320 weight
// tile ONCE PER BLOCK into LDS, double-buffered, laid out in FRAGMENT ORDER
// (lds16B[ks*64 + lane]) so both ds_write (stage) and ds_read (compute) are
// base + lane*16 — linear, zero bank conflicts. Prefetch tile n+1 into regs
// at loop top (issue-early), one barrier per iter:
//   reads of buf B happen before barrier(n); the next write of buf B is in
//   iter n+1 after barrier(n) -> RAW and WAR both safe.
// x B-frags (32 rows) held in regs across the loop; stores in-place (own rows).
// ---------------------------------------------------------------------------
__global__ __launch_bounds__(256) void k_q(u16* qb,
                                           const u16* __restrict__ qwT) {
  __shared__ u16 wlds[2][5120];  // 2 x 10240 B
  const int tid = threadIdx.x, lane = tid & 63;
  const int wv = tid >> 6, quad = lane >> 4, l15 = lane & 15;
  const int r0 = blockIdx.x * 128 + wv * 32;
  const f32x4 fz = {0.f, 0.f, 0.f, 0.f};

  // x fragments for this wave's 32 rows (from xbf overlay in qb)
  bf16x8 Bfr[2][10];
#pragma unroll
  for (int t = 0; t < 2; t++) {
    const u16* xr = qb + (size_t)(r0 + t * 16 + l15) * CN;
#pragma unroll
    for (int ks = 0; ks < 10; ks++)
      Bfr[t][ks] = *(const bf16x8*)(xr + ks * 32 + quad * 8);
  }

  // stage tile n=0: chunk idx -> (ks=idx>>6, q=(idx>>4)&3, l=idx&15)
  for (int idx = tid; idx < 640; idx += 256)
    *(uint4*)(wlds[0] + idx * 8) = *(const uint4*)(
        qwT + (size_t)(idx & 15) * CD + (idx >> 6) * 32 + ((idx >> 4) & 3) * 8);
  __syncthreads();

#pragma unroll 1
  for (int n = 0; n < 25; n++) {
    const u16* wb = wlds[n & 1];
    // prefetch next tile into regs (issue early; lands under the MFMAs)
    uint4 st0, st1, st2;
    const bool h2 = tid < 128;
    if (n < 24) {
      const int base = (n + 1) * 16;
      {
        const int idx = tid;
        st0 = *(const uint4*)(qwT + (size_t)(base + (idx & 15)) * CD +
                              (idx >> 6) * 32 + ((idx >> 4) & 3) * 8);
      }
      {
        const int idx = tid + 256;
        st1 = *(const uint4*)(qwT + (size_t)(base + (idx & 15)) * CD +
                              (idx >> 6) * 32 + ((idx >> 4) & 3) * 8);
      }
      if (h2) {
        const int idx = tid + 512;
        st2 = *(const uint4*)(qwT + (size_t)(base + (idx & 15)) * CD +
                              (idx >> 6) * 32 + ((idx >> 4) & 3) * 8);
      }
    }
    // compute from LDS (linear: base + lane*16, conflict-free)
    f32x4 acc[2] = {fz, fz};
#pragma unroll
    for (int ks = 0; ks < 10; ks++) {
      const bf16x8 A = *(const bf16x8*)(wb + ks * 512 + lane * 8);
      acc[0] = __builtin_amdgcn_mfma_f32_16x16x32_bf16(A, Bfr[0][ks], acc[0], 0, 0, 0);
      acc[1] = __builtin_amdgcn_mfma_f32_16x16x32_bf16(A, Bfr[1][ks], acc[1], 0, 0, 0);
    }
#pragma unroll
    for (int t = 0; t < 2; t++)
      *(uint2*)(qb + (size_t)(r0 + t * 16 + l15) * CN + n * 16 + quad * 4) =
          pack4(acc[t][0], acc[t][1], acc[t][2], acc[t][3]);
    // write next buffer, then the iteration barrier
    if (n < 24) {
      u16* wn = wlds[(n + 1) & 1];
      *(uint4*)(wn + tid * 8) = st0;
      *(uint4*)(wn + (tid + 256) * 8) = st1;
      if (h2) *(uint4*)(wn + (tid + 512) * 8) = st2;
      __syncthreads();
    }
  }
}

// ---------------------------------------------------------------------------
// Kernel 4 v2: attention, OPERAND-SWAPPED, single barrier, P in registers.
// grid (5, 49, 32), 256 threads, LDS 31360 B -> 5 blocks/CU.
//   S^T = mfma(A=Ks, B=q): sacc[n][r] = S[key=n*16+quad*4+r][q-row l15].
//   Softmax per-lane (52 keys) + 2 cross-quad shuffles.
//   PV: O^T = mfma(A=V^T from vt, B=P^T built by 8 cross-quad shuffles/kk).
//   bf16 attn-out written in place into qb (own rows, cols h*80+0..63).
// Ks is exact [196][80]; n=12 A-rows clamp to row 195 (keys 196..207 are
// masked post-GEMM); ks=2 quad>=2 zeroed on BOTH operands (no overreads).
// ---------------------------------------------------------------------------
__global__ __launch_bounds__(256, 5) void k_attn(u16* __restrict__ qb,
                                                 const u16* __restrict__ kb,
                                                 const u16* __restrict__ vt) {
  const int h = blockIdx.x, qt = blockIdx.y, b = blockIdx.z;
  const int tid = threadIdx.x, lane = tid & 63, wv = tid >> 6;
  const int quad = lane >> 4, l15 = lane & 15;
  const int q0 = qt * 64, m0 = wv * 16;
  const f32x4 fz = {0.f, 0.f, 0.f, 0.f};

  __shared__ u16 Ks[196 * 80];  // 31360 B

  // stage K head-slice [196][80] -> Ks, linear (dest byte = idx*16)
  for (int idx = tid; idx < 1960; idx += 256) {
    const int key = idx / 10, g = idx - key * 10;
    *(uint4*)(Ks + idx * 8) =
        *(const uint4*)(kb + ((size_t)(b * NKEY + key)) * CN + h * DQ + g * 8);
  }
  __syncthreads();  // the only barrier

  // ---- S^T (13 key-tiles; K=80 exact, zero-padded to 96 on both operands)
  f32x4 sacc[13];
#pragma unroll
  for (int n = 0; n < 13; n++) sacc[n] = fz;
  {
    union { uint4 u; bf16x8 v; } z;
    z.u = make_uint4(0, 0, 0, 0);
    const u16* qr = qb + (size_t)(b * NN + q0 + m0 + l15) * CN + h * DQ;
    bf16x8 bq0 = *(const bf16x8*)(qr + quad * 8);
    bf16x8 bq1 = *(const bf16x8*)(qr + 32 + quad * 8);
    bf16x8 bq2 = (quad < 2) ? *(const bf16x8*)(qr + 64 + quad * 8) : z.v;
#pragma unroll
    for (int n = 0; n < 13; n++) {
      const int rr = n * 16 + l15;
      const u16* kr = Ks + ((rr > 195) ? 195 : rr) * 80;
      sacc[n] = __builtin_amdgcn_mfma_f32_16x16x32_bf16(
          *(const bf16x8*)(kr + quad * 8), bq0, sacc[n], 0, 0, 0);
      sacc[n] = __builtin_amdgcn_mfma_f32_16x16x32_bf16(
          *(const bf16x8*)(kr + 32 + quad * 8), bq1, sacc[n], 0, 0, 0);
      const bf16x8 ak2 = (quad < 2) ? *(const bf16x8*)(kr + 64 + quad * 8) : z.v;
      sacc[n] = __builtin_amdgcn_mfma_f32_16x16x32_bf16(ak2, bq2, sacc[n], 0, 0, 0);
    }
  }

  // ---- softmax: per-lane over 52 keys, cross-quad via shfl_xor 16/32
  u32 u[13][2];
  {
    float mx = -1e30f;
#pragma unroll
    for (int n = 0; n < 13; n++)
#pragma unroll
      for (int r = 0; r < 4; r++) {
        float s = sacc[n][r] * SCALE_F;
        if (n == 12 && quad != 0) s = -1e30f;  // keys 196..207
        sacc[n][r] = s;
        mx = fmaxf(mx, s);
      }
    mx = fmaxf(mx, __shfl_xor(mx, 16));
    mx = fmaxf(mx, __shfl_xor(mx, 32));
    float sum = 0.f;
#pragma unroll
    for (int n = 0; n < 13; n++)
#pragma unroll
      for (int r = 0; r < 4; r++) {
        const float e = __expf(sacc[n][r] - mx);
        sacc[n][r] = e;
        sum += e;
      }
    sum += __shfl_xor(sum, 16);
    sum += __shfl_xor(sum, 32);
    const float inv = 1.f / sum;
#pragma unroll
    for (int n = 0; n < 13; n++) {
      u[n][0] = (u32)f2bf(sacc[n][0] * inv) | ((u32)f2bf(sacc[n][1] * inv) << 16);
      u[n][1] = (u32)f2bf(sacc[n][2] * inv) | ((u32)f2bf(sacc[n][3] * inv) << 16);
    }
  }

  // ---- O^T = P^T-fed MFMA; B-frags built by cross-quad shuffles
  f32x4 oacc[4];
#pragma unroll
  for (int nn = 0; nn < 4; nn++) oacc[nn] = fz;
  {
    const u16* vbase = vt + (size_t)(b * 320 + h * DV) * 224;
    const int src0 = ((lane & 16) << 1) | l15;  // (quad&1)*32 + l15
    const int src1 = src0 + 16;
    const bool hi = (quad >= 2);
#pragma unroll
    for (int kk = 0; kk < 7; kk++) {
      union { bf16x8 v; u32 w[4]; } bp;
      const u32 a0 = (u32)__shfl((int)u[2 * kk][0], src0);
      const u32 a1 = (u32)__shfl((int)u[2 * kk][1], src0);
      const u32 a2 = (u32)__shfl((int)u[2 * kk][0], src1);
      const u32 a3 = (u32)__shfl((int)u[2 * kk][1], src1);
      u32 b0 = 0, b1 = 0, b2 = 0, b3 = 0;
      if (kk < 6) {
        b0 = (u32)__shfl((int)u[2 * kk + 1][0], src0);
        b1 = (u32)__shfl((int)u[2 * kk + 1][1], src0);
        b2 = (u32)__shfl((int)u[2 * kk + 1][0], src1);
        b3 = (u32)__shfl((int)u[2 * kk + 1][1], src1);
      }
      bp.w[0] = hi ? b0 : a0;
      bp.w[1] = hi ? b1 : a1;
      bp.w[2] = hi ? b2 : a2;
      bp.w[3] = hi ? b3 : a3;
#pragma unroll
      for (int nn = 0; nn < 4; nn++) {
        const bf16x8 A = *(const bf16x8*)(vbase + (size_t)(nn * 16 + l15) * 224 +
                                          kk * 32 + quad * 8);
        oacc[nn] = __builtin_amdgcn_mfma_f32_16x16x32_bf16(A, bp.v, oacc[nn], 0, 0, 0);
      }
    }
  }
  // ---- bf16 attn-out overlay into qb (own rows, cols h*80+0..63)
  u16* orow = qb + (size_t)(b * NN + q0 + m0 + l15) * CN + h * DQ;
#pragma unroll
  for (int nn = 0; nn < 4; nn++)
    *(uint2*)(orow + nn * 16 + quad * 4) =
        pack4(oacc[nn][0], oacc[nn][1], oacc[nn][2], oacc[nn][3]);
}

// ---------------------------------------------------------------------------
// Kernel 5 v3 (OPERAND-SWAPPED, LDS weight staging): out = ao @ proj_w + b.
// Same structure as k_q v3: block = 4 waves x 32 rows, grid 784; pwT n-tile
// (16x320) double-buffered in LDS in fragment order; 20 iters; one barrier
// per iter. ao B-frags (funky head layout) held in regs; float4 stores.
// ---------------------------------------------------------------------------
__global__ __launch_bounds__(256) void k_proj(const u16* __restrict__ ao,
                                              const u16* __restrict__ pwT,
                                              const float* __restrict__ proj_b,
                                              float* __restrict__ out) {
  __shared__ u16 wlds[2][5120];  // 2 x 10240 B
  const int tid = threadIdx.x, lane = tid & 63;
  const int wv = tid >> 6, quad = lane >> 4, l15 = lane & 15;
  const int r0 = blockIdx.x * 128 + wv * 32;
  const f32x4 fz = {0.f, 0.f, 0.f, 0.f};

  bf16x8 Bfr[2][10];
#pragma unroll
  for (int t = 0; t < 2; t++) {
    const u16* xr = ao + (size_t)(r0 + t * 16 + l15) * CN;
#pragma unroll
    for (int ks = 0; ks < 10; ks++)
      Bfr[t][ks] = *(const bf16x8*)(xr + (ks >> 1) * DQ + (ks & 1) * 32 + quad * 8);
  }

  for (int idx = tid; idx < 640; idx += 256)
    *(uint4*)(wlds[0] + idx * 8) = *(const uint4*)(
        pwT + (size_t)(idx & 15) * CD + (idx >> 6) * 32 + ((idx >> 4) & 3) * 8);
  __syncthreads();

#pragma unroll 1
  for (int n = 0; n < 20; n++) {
    const u16* wb = wlds[n & 1];
    uint4 st0, st1, st2;
    const bool h2 = tid < 128;
    if (n < 19) {
      const int base = (n + 1) * 16;
      {
        const int idx = tid;
        st0 = *(const uint4*)(pwT + (size_t)(base + (idx & 15)) * CD +
                              (idx >> 6) * 32 + ((idx >> 4) & 3) * 8);
      }
      {
        const int idx = tid + 256;
        st1 = *(const uint4*)(pwT + (size_t)(base + (idx & 15)) * CD +
                              (idx >> 6) * 32 + ((idx >> 4) & 3) * 8);
      }
      if (h2) {
        const int idx = tid + 512;
        st2 = *(const uint4*)(pwT + (size_t)(base + (idx & 15)) * CD +
                              (idx >> 6) * 32 + ((idx >> 4) & 3) * 8);
      }
    }
    f32x4 acc[2] = {fz, fz};
#pragma unroll
    for (int ks = 0; ks < 10; ks++) {
      const bf16x8 A = *(const bf16x8*)(wb + ks * 512 + lane * 8);
      acc[0] = __builtin_amdgcn_mfma_f32_16x16x32_bf16(A, Bfr[0][ks], acc[0], 0, 0, 0);
      acc[1] = __builtin_amdgcn_mfma_f32_16x16x32_bf16(A, Bfr[1][ks], acc[1], 0, 0, 0);
    }
    const float4 pb = *(const float4*)(proj_b + n * 16 + quad * 4);
#pragma unroll
    for (int t = 0; t < 2; t++) {
      float4 o;
      o.x = acc[t][0] + pb.x;
      o.y = acc[t][1] + pb.y;
      o.z = acc[t][2] + pb.z;
      o.w = acc[t][3] + pb.w;
      *(float4*)(out + (size_t)(r0 + t * 16 + l15) * CD + n * 16 + quad * 4) = o;
    }
    if (n < 19) {
      u16* wn = wlds[(n + 1) & 1];
      *(uint4*)(wn + tid * 8) = st0;
      *(uint4*)(wn + (tid + 256) * 8) = st1;
      if (h2) *(uint4*)(wn + (tid + 512) * 8) = st2;
      __syncthreads();
    }
  }
}

// ---------------------------------------------------------------------------
extern "C" void kernel_launch(void* const* d_in, const int* in_sizes, int n_in,
                              void* d_out, int out_size, void* d_ws,
                              size_t ws_size, hipStream_t stream) {
  const float* x = (const float*)d_in[0];
  const float* dw_w = (const float*)d_in[3];
  const float* dw_b = (const float*)d_in[4];
  const float* pw_w = (const float*)d_in[5];
  const float* pw_b = (const float*)d_in[6];
  const float* ln_g = (const float*)d_in[7];
  const float* ln_b = (const float*)d_in[8];
  const float* q_w = (const float*)d_in[9];
  const float* k_w = (const float*)d_in[10];
  const float* v_w = (const float*)d_in[11];
  const float* proj_w = (const float*)d_in[12];
  const float* proj_b = (const float*)d_in[13];
  float* out = (float*)d_out;

  u16* w = (u16*)d_ws;
  u16* xs16 = w;                    // [6272][416]       = 2,609,152  (hosts dwc16 overlay)
  u16* kb16 = xs16 + 2609152;       // [6272][400]       = 2,508,800
  u16* vt16 = kb16 + 2508800;       // [32*320][224]     = 2,293,760
  u16* qb16 = vt16 + 2293760;       // [100352][400]+64  = 40,140,864 (hosts xbf + ao overlays)
  u16* qwT = qb16 + 40140864;       // [400][320]        = 128,000
  u16* pwT = qwT + 128000;          // [320][320]        = 102,400
  u16* kvwT = pwT + 102400;         // [720][416]        = 299,520
  u16* pwb = kvwT + 299520;         // [400][320]        = 128,000
                                    // total ~96.5 MB

  k_prep<<<512, 256, 0, stream>>>(q_w, proj_w, k_w, v_w, pw_w, qwT, pwT, kvwT,
                                  pwb);
  k_dw<<<1960, 256, 0, stream>>>(x, dw_w, dw_b, xs16 /*dwc16 overlay*/,
                                 qb16 /*xbf overlay*/);
  k_pwln<<<392, 64, 0, stream>>>(xs16, pwb, pw_b, ln_g, ln_b);
  k_kv<<<dim3(392, 3), 64, 0, stream>>>(xs16, kvwT, kb16, vt16);
  k_q<<<784, 256, 0, stream>>>(qb16, qwT);
  k_attn<<<dim3(NH, 49, NB), 256, 0, stream>>>(qb16, kb16, vt16);
  k_proj<<<784, 256, 0, stream>>>(qb16, pwT, proj_b, out);
}

// Round 8
// 538.389 us; speedup vs baseline: 1.5280x; 1.0863x over previous
//
#include <hip/hip_runtime.h>
#include <math.h>

#define NB 32
#define NN 3136
#define CD 320
#define NH 5
#define CN 400
#define NKEY 196
#define DQ 80
#define DV 64
#define SCALE_F 0.11180339887498949f

typedef __bf16 bf16x8 __attribute__((ext_vector_type(8)));
typedef float f32x4 __attribute__((ext_vector_type(4)));
typedef unsigned short u16;
typedef unsigned int u32;

__device__ __forceinline__ u16 f2bf(float f) {
  u32 u = __float_as_uint(f);
  u += 0x7fffu + ((u >> 16) & 1u);  // round-to-nearest-even
  return (u16)(u >> 16);
}

__device__ __forceinline__ uint2 pack4(float a, float b, float c, float d) {
  return make_uint2((u32)f2bf(a) | ((u32)f2bf(b) << 16),
                    (u32)f2bf(c) | ((u32)f2bf(d) << 16));
}

// ---------------------------------------------------------------------------
// Prep: qwT bf16 [400][320]; pwT bf16 [320][320]; kvwT bf16 [720][416]
// (rows 0..399 = k_w^T, rows 400..719 = v_w^T, cols 400..415 zero);
// pwb bf16 [400][320] = pw_w cast (native out-major layout).
// ---------------------------------------------------------------------------
__global__ void k_prep(const float* __restrict__ q_w,
                       const float* __restrict__ proj_w,
                       const float* __restrict__ k_w,
                       const float* __restrict__ v_w,
                       const float* __restrict__ pw_w, u16* __restrict__ qwT,
                       u16* __restrict__ pwT, u16* __restrict__ kvwT,
                       u16* __restrict__ pwb) {
  const int i0 = blockIdx.x * 256 + threadIdx.x;
  const int stride = gridDim.x * 256;
  for (int idx = i0; idx < 400 * 320; idx += stride) {
    const int o = idx / 320, c = idx - o * 320;
    qwT[idx] = f2bf(q_w[(size_t)c * 400 + o]);
  }
  for (int idx = i0; idx < 320 * 320; idx += stride) {
    const int o = idx / 320, c = idx - o * 320;
    pwT[idx] = f2bf(proj_w[(size_t)c * 320 + o]);
  }
  for (int idx = i0; idx < 400 * 320; idx += stride) {
    pwb[idx] = f2bf(pw_w[idx]);
  }
  for (int idx = i0; idx < 720 * 416; idx += stride) {
    const int o = idx / 416, c = idx - o * 416;
    float v = 0.f;
    if (c < 400) v = (o < 400) ? k_w[(size_t)c * 400 + o] : v_w[(size_t)c * 320 + (o - 400)];
    kvwT[idx] = f2bf(v);
  }
}

// ---------------------------------------------------------------------------
// Kernel 1a: depthwise 4x4/s4 conv, pure streaming; each x element is read by
// exactly one thread, so we ALSO emit the bf16 cast of x:
//   xbf  = bf16 x, overlaid in the qb region (row stride 400, cols 0..319)
//   dwc16 = bf16 dw-conv output, overlaid in the xs region (stride 416)
// grid 1960 (= 6272*80/256), thread = 4 channels of one output pixel.
// ---------------------------------------------------------------------------
__global__ __launch_bounds__(256) void k_dw(const float* __restrict__ x,
                                            const float* __restrict__ dw_w,
                                            const float* __restrict__ dw_b,
                                            u16* __restrict__ dwc16,
                                            u16* __restrict__ xbf) {
  const int idx = blockIdx.x * 256 + threadIdx.x;  // 6272*80
  const int row = idx / 80, c4 = (idx - row * 80) * 4;
  const int b = row / 196, pl = row - b * 196;
  const int oh = pl / 14, ow = pl - oh * 14;
  const size_t pix0 = (size_t)b * NN + (size_t)(oh * 4) * 56 + ow * 4;
  const float* xb = x + pix0 * CD + c4;

  float w[4][16];
#pragma unroll
  for (int k = 0; k < 4; k++)
#pragma unroll
    for (int j4 = 0; j4 < 4; j4++)
      *(float4*)&w[k][j4 * 4] = *(const float4*)(dw_w + (c4 + k) * 16 + j4 * 4);

  float a0 = dw_b[c4], a1 = dw_b[c4 + 1], a2 = dw_b[c4 + 2], a3 = dw_b[c4 + 3];
#pragma unroll
  for (int i = 0; i < 4; i++)
#pragma unroll
    for (int j = 0; j < 4; j++) {
      const float4 xv = *(const float4*)(xb + (size_t)(i * 56 + j) * CD);
      const int t = i * 4 + j;
      a0 += xv.x * w[0][t];
      a1 += xv.y * w[1][t];
      a2 += xv.z * w[2][t];
      a3 += xv.w * w[3][t];
      *(uint2*)(xbf + (pix0 + i * 56 + j) * CN + c4) =
          pack4(xv.x, xv.y, xv.z, xv.w);
    }
  *(uint2*)(dwc16 + (size_t)row * 416 + c4) = pack4(a0, a1, a2, a3);
}

// ---------------------------------------------------------------------------
// Kernel 1b v2: 1x1 conv + LN + GELU, N-SPLIT across 4 waves.
// Round-7 diagnosis: v1 ran 392 waves total (4.8% occupancy), each streaming
// the full 256KB pwb from L2 — the round-6 k_q pathology. LN forces whole
// rows per block, so we add waves by splitting N: block = 256 thr, all 4
// waves share the 16 rows (row0 = bx*16); wave wv owns n-tiles wv+4j.
// LN stats: per-wave partial -> 512B LDS -> one barrier -> combine.
// Weight L2 traffic /4 (each tile read once per block), 1568 waves.
// In-place in xs: reads dwc16 (cols 0..319), writes cols 0..399 (all Bfr
// loads precede the barrier; all stores follow it).
// ---------------------------------------------------------------------------
__global__ __launch_bounds__(256) void k_pwln(u16* xs,
                                              const u16* __restrict__ pwb,
                                              const float* __restrict__ pw_b,
                                              const float* __restrict__ ln_g,
                                              const float* __restrict__ ln_b) {
  __shared__ float redS[4][16], redQ[4][16];
  const int tid = threadIdx.x, lane = tid & 63, wv = tid >> 6;
  const int quad = lane >> 4, l15 = lane & 15;
  const int row0 = blockIdx.x * 16;
  const f32x4 fz = {0.f, 0.f, 0.f, 0.f};

  bf16x8 Bfr[10];
  {
    const u16* xr = xs + (size_t)(row0 + l15) * 416;
#pragma unroll
    for (int ks = 0; ks < 10; ks++)
      Bfr[ks] = *(const bf16x8*)(xr + ks * 32 + quad * 8);
  }
  f32x4 acc[7];
#pragma unroll
  for (int j = 0; j < 7; j++) acc[j] = fz;
#pragma unroll
  for (int j = 0; j < 7; j++) {
    const int n = wv + 4 * j;
    if (n < 25) {
      const u16* wr = pwb + (size_t)(n * 16 + l15) * CD;
#pragma unroll
      for (int ks = 0; ks < 10; ks++) {
        const bf16x8 A = *(const bf16x8*)(wr + ks * 32 + quad * 8);
        acc[j] = __builtin_amdgcn_mfma_f32_16x16x32_bf16(A, Bfr[ks], acc[j], 0, 0, 0);
      }
      const float4 pb = *(const float4*)(pw_b + n * 16 + quad * 4);
      acc[j][0] += pb.x; acc[j][1] += pb.y; acc[j][2] += pb.z; acc[j][3] += pb.w;
    }
  }
  // per-wave partial LN stats for row l15 (unused acc[] stay zero: harmless)
  float s = 0.f, ss = 0.f;
#pragma unroll
  for (int j = 0; j < 7; j++)
#pragma unroll
    for (int r = 0; r < 4; r++) {
      s += acc[j][r];
      ss += acc[j][r] * acc[j][r];
    }
  s += __shfl_xor(s, 16); ss += __shfl_xor(ss, 16);
  s += __shfl_xor(s, 32); ss += __shfl_xor(ss, 32);
  if (lane < 16) {
    redS[wv][l15] = s;
    redQ[wv][l15] = ss;
  }
  __syncthreads();
  s = redS[0][l15] + redS[1][l15] + redS[2][l15] + redS[3][l15];
  ss = redQ[0][l15] + redQ[1][l15] + redQ[2][l15] + redQ[3][l15];
  const float mu = s * (1.f / 400.f);
  const float var = ss * (1.f / 400.f) - mu * mu;
  const float rstd = rsqrtf(var + 1e-5f);

  u16* orow = xs + (size_t)(row0 + l15) * 416;
#pragma unroll
  for (int j = 0; j < 7; j++) {
    const int n = wv + 4 * j;
    if (n < 25) {
      const float4 g = *(const float4*)(ln_g + n * 16 + quad * 4);
      const float4 bb = *(const float4*)(ln_b + n * 16 + quad * 4);
      float ge[4];
#pragma unroll
      for (int r = 0; r < 4; r++) {
        const float gg = (&g.x)[r], bv = (&bb.x)[r];
        const float v = (acc[j][r] - mu) * rstd * gg + bv;
        ge[r] = 0.5f * v * (1.f + erff(v * 0.70710678118654752f));
      }
      *(uint2*)(orow + n * 16 + quad * 4) = pack4(ge[0], ge[1], ge[2], ge[3]);
    }
  }
  if (wv == 3) *(uint2*)(orow + 400 + quad * 4) = make_uint2(0, 0);
}

// ---------------------------------------------------------------------------
// Kernel 2 v2 (MFMA, LDS weight staging): xs @ kvwT^T -> kb / vt.
// k_q-v3 template: grid (98, 9), 4 waves x 16 rows; nt-range = by*5..+5.
// kvwT n-tile [16][416] double-buffered in LDS in FRAGMENT ORDER
// (chunk16B[ks*64 + lane]) -> linear ds_write/ds_read, conflict-free.
// Reg-prefetch of tile j+1 issued before the MFMAs; one barrier per iter
// (reads of cur buf before barrier, next write of it after -> RAW+WAR safe).
// 3528 waves (was 1176); weights from LDS instead of per-wave L2 streams.
// Store code identical to v1.
// ---------------------------------------------------------------------------
__global__ __launch_bounds__(256) void k_kv(const u16* __restrict__ xs,
                                            const u16* __restrict__ kvwT,
                                            u16* __restrict__ kb,
                                            u16* __restrict__ vt) {
  __shared__ u16 wlds[2][6656];  // 2 x 13312 B
  const int tid = threadIdx.x, lane = tid & 63, wv = tid >> 6;
  const int quad = lane >> 4, l15 = lane & 15;
  const int mt = blockIdx.x * 4 + wv;  // 0..391
  const int nt0 = blockIdx.y * 5;      // 0,5,...,40
  const f32x4 fz = {0.f, 0.f, 0.f, 0.f};

  bf16x8 A[13];
  {
    const u16* xr = xs + (size_t)(mt * 16 + l15) * 416;
#pragma unroll
    for (int ks = 0; ks < 13; ks++)
      A[ks] = *(const bf16x8*)(xr + ks * 32 + quad * 8);
  }

  // stage tile nt0: chunk idx -> (ks=idx>>6, ln=idx&63 -> q,l)
  for (int idx = tid; idx < 832; idx += 256) {
    const int ks = idx >> 6, ln = idx & 63, q = ln >> 4, l = ln & 15;
    *(uint4*)(wlds[0] + idx * 8) = *(const uint4*)(
        kvwT + (size_t)(nt0 * 16 + l) * 416 + ks * 32 + q * 8);
  }
  __syncthreads();

#pragma unroll 1
  for (int j = 0; j < 5; j++) {
    const int nt = nt0 + j;
    const u16* wb = wlds[j & 1];
    // prefetch next tile into regs (832 chunks: 3 full rounds + 64)
    uint4 st0, st1, st2, st3;
    const bool t4 = tid < 64;
    if (j < 4) {
      const int base = (nt + 1) * 16;
      {
        const int idx = tid;
        const int ks = idx >> 6, ln = idx & 63, q = ln >> 4, l = ln & 15;
        st0 = *(const uint4*)(kvwT + (size_t)(base + l) * 416 + ks * 32 + q * 8);
      }
      {
        const int idx = tid + 256;
        const int ks = idx >> 6, ln = idx & 63, q = ln >> 4, l = ln & 15;
        st1 = *(const uint4*)(kvwT + (size_t)(base + l) * 416 + ks * 32 + q * 8);
      }
      {
        const int idx = tid + 512;
        const int ks = idx >> 6, ln = idx & 63, q = ln >> 4, l = ln & 15;
        st2 = *(const uint4*)(kvwT + (size_t)(base + l) * 416 + ks * 32 + q * 8);
      }
      if (t4) {
        const int idx = tid + 768;
        const int ks = idx >> 6, ln = idx & 63, q = ln >> 4, l = ln & 15;
        st3 = *(const uint4*)(kvwT + (size_t)(base + l) * 416 + ks * 32 + q * 8);
      }
    }
    // compute from LDS (linear: base + lane*16, conflict-free)
    f32x4 acc = fz;
#pragma unroll
    for (int ks = 0; ks < 13; ks++) {
      const bf16x8 B = *(const bf16x8*)(wb + ks * 512 + lane * 8);
      acc = __builtin_amdgcn_mfma_f32_16x16x32_bf16(A[ks], B, acc, 0, 0, 0);
    }
    const int col = nt * 16 + l15;
    if (col < 400) {
#pragma unroll
      for (int r = 0; r < 4; r++)
        kb[(size_t)(mt * 16 + quad * 4 + r) * 400 + col] = f2bf(acc[r]);
    } else {
      const int vo = col - 400;
#pragma unroll
      for (int r = 0; r < 4; r++) {
        const int row = mt * 16 + quad * 4 + r;
        const int bb = row / 196, key = row - bb * 196;
        vt[((size_t)(bb * 320 + vo)) * 224 + key] = f2bf(acc[r]);
      }
    }
    if (j < 4) {
      u16* wn = wlds[(j + 1) & 1];
      *(uint4*)(wn + tid * 8) = st0;
      *(uint4*)(wn + (tid + 256) * 8) = st1;
      *(uint4*)(wn + (tid + 512) * 8) = st2;
      if (t4) *(uint4*)(wn + (tid + 768) * 8) = st3;
      __syncthreads();
    }
  }
}

// ---------------------------------------------------------------------------
// Kernel 3 v3 (MFMA, OPERAND-SWAPPED, IN-PLACE, LDS weight staging):
// qb = x @ q_w. Block = 4 waves x 32 rows = 128 rows, grid 784.
// Stages each 16x320 weight tile ONCE PER BLOCK into LDS, double-buffered,
// fragment order -> linear ds ops, conflict-free. One barrier per iter.
// ---------------------------------------------------------------------------
__global__ __launch_bounds__(256) void k_q(u16* qb,
                                           const u16* __restrict__ qwT) {
  __shared__ u16 wlds[2][5120];  // 2 x 10240 B
  const int tid = threadIdx.x, lane = tid & 63;
  const int wv = tid >> 6, quad = lane >> 4, l15 = lane & 15;
  const int r0 = blockIdx.x * 128 + wv * 32;
  const f32x4 fz = {0.f, 0.f, 0.f, 0.f};

  // x fragments for this wave's 32 rows (from xbf overlay in qb)
  bf16x8 Bfr[2][10];
#pragma unroll
  for (int t = 0; t < 2; t++) {
    const u16* xr = qb + (size_t)(r0 + t * 16 + l15) * CN;
#pragma unroll
    for (int ks = 0; ks < 10; ks++)
      Bfr[t][ks] = *(const bf16x8*)(xr + ks * 32 + quad * 8);
  }

  // stage tile n=0: chunk idx -> (ks=idx>>6, q=(idx>>4)&3, l=idx&15)
  for (int idx = tid; idx < 640; idx += 256)
    *(uint4*)(wlds[0] + idx * 8) = *(const uint4*)(
        qwT + (size_t)(idx & 15) * CD + (idx >> 6) * 32 + ((idx >> 4) & 3) * 8);
  __syncthreads();

#pragma unroll 1
  for (int n = 0; n < 25; n++) {
    const u16* wb = wlds[n & 1];
    // prefetch next tile into regs (issue early; lands under the MFMAs)
    uint4 st0, st1, st2;
    const bool h2 = tid < 128;
    if (n < 24) {
      const int base = (n + 1) * 16;
      {
        const int idx = tid;
        st0 = *(const uint4*)(qwT + (size_t)(base + (idx & 15)) * CD +
                              (idx >> 6) * 32 + ((idx >> 4) & 3) * 8);
      }
      {
        const int idx = tid + 256;
        st1 = *(const uint4*)(qwT + (size_t)(base + (idx & 15)) * CD +
                              (idx >> 6) * 32 + ((idx >> 4) & 3) * 8);
      }
      if (h2) {
        const int idx = tid + 512;
        st2 = *(const uint4*)(qwT + (size_t)(base + (idx & 15)) * CD +
                              (idx >> 6) * 32 + ((idx >> 4) & 3) * 8);
      }
    }
    // compute from LDS (linear: base + lane*16, conflict-free)
    f32x4 acc[2] = {fz, fz};
#pragma unroll
    for (int ks = 0; ks < 10; ks++) {
      const bf16x8 A = *(const bf16x8*)(wb + ks * 512 + lane * 8);
      acc[0] = __builtin_amdgcn_mfma_f32_16x16x32_bf16(A, Bfr[0][ks], acc[0], 0, 0, 0);
      acc[1] = __builtin_amdgcn_mfma_f32_16x16x32_bf16(A, Bfr[1][ks], acc[1], 0, 0, 0);
    }
#pragma unroll
    for (int t = 0; t < 2; t++)
      *(uint2*)(qb + (size_t)(r0 + t * 16 + l15) * CN + n * 16 + quad * 4) =
          pack4(acc[t][0], acc[t][1], acc[t][2], acc[t][3]);
    // write next buffer, then the iteration barrier
    if (n < 24) {
      u16* wn = wlds[(n + 1) & 1];
      *(uint4*)(wn + tid * 8) = st0;
      *(uint4*)(wn + (tid + 256) * 8) = st1;
      if (h2) *(uint4*)(wn + (tid + 512) * 8) = st2;
      __syncthreads();
    }
  }
}

// ---------------------------------------------------------------------------
// Kernel 4 v2: attention, OPERAND-SWAPPED, single barrier, P in registers.
// grid (5, 49, 32), 256 threads, LDS 31360 B -> 5 blocks/CU.
//   S^T = mfma(A=Ks, B=q): sacc[n][r] = S[key=n*16+quad*4+r][q-row l15].
//   Softmax per-lane (52 keys) + 2 cross-quad shuffles.
//   PV: O^T = mfma(A=V^T from vt, B=P^T built by 8 cross-quad shuffles/kk).
//   bf16 attn-out written in place into qb (own rows, cols h*80+0..63).
// Ks is exact [196][80]; n=12 A-rows clamp to row 195 (keys 196..207 are
// masked post-GEMM); ks=2 quad>=2 zeroed on BOTH operands (no overreads).
// ---------------------------------------------------------------------------
__global__ __launch_bounds__(256, 5) void k_attn(u16* __restrict__ qb,
                                                 const u16* __restrict__ kb,
                                                 const u16* __restrict__ vt) {
  const int h = blockIdx.x, qt = blockIdx.y, b = blockIdx.z;
  const int tid = threadIdx.x, lane = tid & 63, wv = tid >> 6;
  const int quad = lane >> 4, l15 = lane & 15;
  const int q0 = qt * 64, m0 = wv * 16;
  const f32x4 fz = {0.f, 0.f, 0.f, 0.f};

  __shared__ u16 Ks[196 * 80];  // 31360 B

  // stage K head-slice [196][80] -> Ks, linear (dest byte = idx*16)
  for (int idx = tid; idx < 1960; idx += 256) {
    const int key = idx / 10, g = idx - key * 10;
    *(uint4*)(Ks + idx * 8) =
        *(const uint4*)(kb + ((size_t)(b * NKEY + key)) * CN + h * DQ + g * 8);
  }
  __syncthreads();  // the only barrier

  // ---- S^T (13 key-tiles; K=80 exact, zero-padded to 96 on both operands)
  f32x4 sacc[13];
#pragma unroll
  for (int n = 0; n < 13; n++) sacc[n] = fz;
  {
    union { uint4 u; bf16x8 v; } z;
    z.u = make_uint4(0, 0, 0, 0);
    const u16* qr = qb + (size_t)(b * NN + q0 + m0 + l15) * CN + h * DQ;
    bf16x8 bq0 = *(const bf16x8*)(qr + quad * 8);
    bf16x8 bq1 = *(const bf16x8*)(qr + 32 + quad * 8);
    bf16x8 bq2 = (quad < 2) ? *(const bf16x8*)(qr + 64 + quad * 8) : z.v;
#pragma unroll
    for (int n = 0; n < 13; n++) {
      const int rr = n * 16 + l15;
      const u16* kr = Ks + ((rr > 195) ? 195 : rr) * 80;
      sacc[n] = __builtin_amdgcn_mfma_f32_16x16x32_bf16(
          *(const bf16x8*)(kr + quad * 8), bq0, sacc[n], 0, 0, 0);
      sacc[n] = __builtin_amdgcn_mfma_f32_16x16x32_bf16(
          *(const bf16x8*)(kr + 32 + quad * 8), bq1, sacc[n], 0, 0, 0);
      const bf16x8 ak2 = (quad < 2) ? *(const bf16x8*)(kr + 64 + quad * 8) : z.v;
      sacc[n] = __builtin_amdgcn_mfma_f32_16x16x32_bf16(ak2, bq2, sacc[n], 0, 0, 0);
    }
  }

  // ---- softmax: per-lane over 52 keys, cross-quad via shfl_xor 16/32
  u32 u[13][2];
  {
    float mx = -1e30f;
#pragma unroll
    for (int n = 0; n < 13; n++)
#pragma unroll
      for (int r = 0; r < 4; r++) {
        float s = sacc[n][r] * SCALE_F;
        if (n == 12 && quad != 0) s = -1e30f;  // keys 196..207
        sacc[n][r] = s;
        mx = fmaxf(mx, s);
      }
    mx = fmaxf(mx, __shfl_xor(mx, 16));
    mx = fmaxf(mx, __shfl_xor(mx, 32));
    float sum = 0.f;
#pragma unroll
    for (int n = 0; n < 13; n++)
#pragma unroll
      for (int r = 0; r < 4; r++) {
        const float e = __expf(sacc[n][r] - mx);
        sacc[n][r] = e;
        sum += e;
      }
    sum += __shfl_xor(sum, 16);
    sum += __shfl_xor(sum, 32);
    const float inv = 1.f / sum;
#pragma unroll
    for (int n = 0; n < 13; n++) {
      u[n][0] = (u32)f2bf(sacc[n][0] * inv) | ((u32)f2bf(sacc[n][1] * inv) << 16);
      u[n][1] = (u32)f2bf(sacc[n][2] * inv) | ((u32)f2bf(sacc[n][3] * inv) << 16);
    }
  }

  // ---- O^T = P^T-fed MFMA; B-frags built by cross-quad shuffles
  f32x4 oacc[4];
#pragma unroll
  for (int nn = 0; nn < 4; nn++) oacc[nn] = fz;
  {
    const u16* vbase = vt + (size_t)(b * 320 + h * DV) * 224;
    const int src0 = ((lane & 16) << 1) | l15;  // (quad&1)*32 + l15
    const int src1 = src0 + 16;
    const bool hi = (quad >= 2);
#pragma unroll
    for (int kk = 0; kk < 7; kk++) {
      union { bf16x8 v; u32 w[4]; } bp;
      const u32 a0 = (u32)__shfl((int)u[2 * kk][0], src0);
      const u32 a1 = (u32)__shfl((int)u[2 * kk][1], src0);
      const u32 a2 = (u32)__shfl((int)u[2 * kk][0], src1);
      const u32 a3 = (u32)__shfl((int)u[2 * kk][1], src1);
      u32 b0 = 0, b1 = 0, b2 = 0, b3 = 0;
      if (kk < 6) {
        b0 = (u32)__shfl((int)u[2 * kk + 1][0], src0);
        b1 = (u32)__shfl((int)u[2 * kk + 1][1], src0);
        b2 = (u32)__shfl((int)u[2 * kk + 1][0], src1);
        b3 = (u32)__shfl((int)u[2 * kk + 1][1], src1);
      }
      bp.w[0] = hi ? b0 : a0;
      bp.w[1] = hi ? b1 : a1;
      bp.w[2] = hi ? b2 : a2;
      bp.w[3] = hi ? b3 : a3;
#pragma unroll
      for (int nn = 0; nn < 4; nn++) {
        const bf16x8 A = *(const bf16x8*)(vbase + (size_t)(nn * 16 + l15) * 224 +
                                          kk * 32 + quad * 8);
        oacc[nn] = __builtin_amdgcn_mfma_f32_16x16x32_bf16(A, bp.v, oacc[nn], 0, 0, 0);
      }
    }
  }
  // ---- bf16 attn-out overlay into qb (own rows, cols h*80+0..63)
  u16* orow = qb + (size_t)(b * NN + q0 + m0 + l15) * CN + h * DQ;
#pragma unroll
  for (int nn = 0; nn < 4; nn++)
    *(uint2*)(orow + nn * 16 + quad * 4) =
        pack4(oacc[nn][0], oacc[nn][1], oacc[nn][2], oacc[nn][3]);
}

// ---------------------------------------------------------------------------
// Kernel 5 v3 (OPERAND-SWAPPED, LDS weight staging): out = ao @ proj_w + b.
// Same structure as k_q v3: block = 4 waves x 32 rows, grid 784; pwT n-tile
// (16x320) double-buffered in LDS in fragment order; 20 iters; one barrier
// per iter. ao B-frags (funky head layout) held in regs; float4 stores.
// ---------------------------------------------------------------------------
__global__ __launch_bounds__(256) void k_proj(const u16* __restrict__ ao,
                                              const u16* __restrict__ pwT,
                                              const float* __restrict__ proj_b,
                                              float* __restrict__ out) {
  __shared__ u16 wlds[2][5120];  // 2 x 10240 B
  const int tid = threadIdx.x, lane = tid & 63;
  const int wv = tid >> 6, quad = lane >> 4, l15 = lane & 15;
  const int r0 = blockIdx.x * 128 + wv * 32;
  const f32x4 fz = {0.f, 0.f, 0.f, 0.f};

  bf16x8 Bfr[2][10];
#pragma unroll
  for (int t = 0; t < 2; t++) {
    const u16* xr = ao + (size_t)(r0 + t * 16 + l15) * CN;
#pragma unroll
    for (int ks = 0; ks < 10; ks++)
      Bfr[t][ks] = *(const bf16x8*)(xr + (ks >> 1) * DQ + (ks & 1) * 32 + quad * 8);
  }

  for (int idx = tid; idx < 640; idx += 256)
    *(uint4*)(wlds[0] + idx * 8) = *(const uint4*)(
        pwT + (size_t)(idx & 15) * CD + (idx >> 6) * 32 + ((idx >> 4) & 3) * 8);
  __syncthreads();

#pragma unroll 1
  for (int n = 0; n < 20; n++) {
    const u16* wb = wlds[n & 1];
    uint4 st0, st1, st2;
    const bool h2 = tid < 128;
    if (n < 19) {
      const int base = (n + 1) * 16;
      {
        const int idx = tid;
        st0 = *(const uint4*)(pwT + (size_t)(base + (idx & 15)) * CD +
                              (idx >> 6) * 32 + ((idx >> 4) & 3) * 8);
      }
      {
        const int idx = tid + 256;
        st1 = *(const uint4*)(pwT + (size_t)(base + (idx & 15)) * CD +
                              (idx >> 6) * 32 + ((idx >> 4) & 3) * 8);
      }
      if (h2) {
        const int idx = tid + 512;
        st2 = *(const uint4*)(pwT + (size_t)(base + (idx & 15)) * CD +
                              (idx >> 6) * 32 + ((idx >> 4) & 3) * 8);
      }
    }
    f32x4 acc[2] = {fz, fz};
#pragma unroll
    for (int ks = 0; ks < 10; ks++) {
      const bf16x8 A = *(const bf16x8*)(wb + ks * 512 + lane * 8);
      acc[0] = __builtin_amdgcn_mfma_f32_16x16x32_bf16(A, Bfr[0][ks], acc[0], 0, 0, 0);
      acc[1] = __builtin_amdgcn_mfma_f32_16x16x32_bf16(A, Bfr[1][ks], acc[1], 0, 0, 0);
    }
    const float4 pb = *(const float4*)(proj_b + n * 16 + quad * 4);
#pragma unroll
    for (int t = 0; t < 2; t++) {
      float4 o;
      o.x = acc[t][0] + pb.x;
      o.y = acc[t][1] + pb.y;
      o.z = acc[t][2] + pb.z;
      o.w = acc[t][3] + pb.w;
      *(float4*)(out + (size_t)(r0 + t * 16 + l15) * CD + n * 16 + quad * 4) = o;
    }
    if (n < 19) {
      u16* wn = wlds[(n + 1) & 1];
      *(uint4*)(wn + tid * 8) = st0;
      *(uint4*)(wn + (tid + 256) * 8) = st1;
      if (h2) *(uint4*)(wn + (tid + 512) * 8) = st2;
      __syncthreads();
    }
  }
}

// ---------------------------------------------------------------------------
extern "C" void kernel_launch(void* const* d_in, const int* in_sizes, int n_in,
                              void* d_out, int out_size, void* d_ws,
                              size_t ws_size, hipStream_t stream) {
  const float* x = (const float*)d_in[0];
  const float* dw_w = (const float*)d_in[3];
  const float* dw_b = (const float*)d_in[4];
  const float* pw_w = (const float*)d_in[5];
  const float* pw_b = (const float*)d_in[6];
  const float* ln_g = (const float*)d_in[7];
  const float* ln_b = (const float*)d_in[8];
  const float* q_w = (const float*)d_in[9];
  const float* k_w = (const float*)d_in[10];
  const float* v_w = (const float*)d_in[11];
  const float* proj_w = (const float*)d_in[12];
  const float* proj_b = (const float*)d_in[13];
  float* out = (float*)d_out;

  u16* w = (u16*)d_ws;
  u16* xs16 = w;                    // [6272][416]       = 2,609,152  (hosts dwc16 overlay)
  u16* kb16 = xs16 + 2609152;       // [6272][400]       = 2,508,800
  u16* vt16 = kb16 + 2508800;       // [32*320][224]     = 2,293,760
  u16* qb16 = vt16 + 2293760;       // [100352][400]+64  = 40,140,864 (hosts xbf + ao overlays)
  u16* qwT = qb16 + 40140864;       // [400][320]        = 128,000
  u16* pwT = qwT + 128000;          // [320][320]        = 102,400
  u16* kvwT = pwT + 102400;         // [720][416]        = 299,520
  u16* pwb = kvwT + 299520;         // [400][320]        = 128,000
                                    // total ~96.5 MB

  k_prep<<<512, 256, 0, stream>>>(q_w, proj_w, k_w, v_w, pw_w, qwT, pwT, kvwT,
                                  pwb);
  k_dw<<<1960, 256, 0, stream>>>(x, dw_w, dw_b, xs16 /*dwc16 overlay*/,
                                 qb16 /*xbf overlay*/);
  k_pwln<<<392, 256, 0, stream>>>(xs16, pwb, pw_b, ln_g, ln_b);
  k_kv<<<dim3(98, 9), 256, 0, stream>>>(xs16, kvwT, kb16, vt16);
  k_q<<<784, 256, 0, stream>>>(qb16, qwT);
  k_attn<<<dim3(NH, 49, NB), 256, 0, stream>>>(qb16, kb16, vt16);
  k_proj<<<784, 256, 0, stream>>>(qb16, pwT, proj_b, out);
}

// Round 9
// 533.676 us; speedup vs baseline: 1.5415x; 1.0088x over previous
//
#include <hip/hip_runtime.h>
#include <math.h>

#define NB 32
#define NN 3136
#define CD 320
#define NH 5
#define CN 400
#define NKEY 196
#define DQ 80
#define DV 64
#define SCALE_F 0.11180339887498949f

typedef __bf16 bf16x8 __attribute__((ext_vector_type(8)));
typedef float f32x4 __attribute__((ext_vector_type(4)));
typedef unsigned short u16;
typedef unsigned int u32;

#if __has_builtin(__builtin_amdgcn_exp2f)
#define EXP2F(x) __builtin_amdgcn_exp2f(x)
#else
#define EXP2F(x) __expf((x)*0.6931471805599453f)
#endif

__device__ __forceinline__ u16 f2bf(float f) {
  u32 u = __float_as_uint(f);
  u += 0x7fffu + ((u >> 16) & 1u);  // round-to-nearest-even
  return (u16)(u >> 16);
}

__device__ __forceinline__ uint2 pack4(float a, float b, float c, float d) {
  return make_uint2((u32)f2bf(a) | ((u32)f2bf(b) << 16),
                    (u32)f2bf(c) | ((u32)f2bf(d) << 16));
}

// hardware packed f32->bf16 (RNE, same rounding as f2bf)
__device__ __forceinline__ u32 cvtpk(float lo, float hi) {
  u32 r;
  asm("v_cvt_pk_bf16_f32 %0, %1, %2" : "=v"(r) : "v"(lo), "v"(hi));
  return r;
}

// ---------------------------------------------------------------------------
// Prep: qwT bf16 [400][320]; pwT bf16 [320][320]; kvwT bf16 [720][416]
// (rows 0..399 = k_w^T, rows 400..719 = v_w^T, cols 400..415 zero);
// pwb bf16 [400][320] = pw_w cast (native out-major layout).
// ---------------------------------------------------------------------------
__global__ void k_prep(const float* __restrict__ q_w,
                       const float* __restrict__ proj_w,
                       const float* __restrict__ k_w,
                       const float* __restrict__ v_w,
                       const float* __restrict__ pw_w, u16* __restrict__ qwT,
                       u16* __restrict__ pwT, u16* __restrict__ kvwT,
                       u16* __restrict__ pwb) {
  const int i0 = blockIdx.x * 256 + threadIdx.x;
  const int stride = gridDim.x * 256;
  for (int idx = i0; idx < 400 * 320; idx += stride) {
    const int o = idx / 320, c = idx - o * 320;
    qwT[idx] = f2bf(q_w[(size_t)c * 400 + o]);
  }
  for (int idx = i0; idx < 320 * 320; idx += stride) {
    const int o = idx / 320, c = idx - o * 320;
    pwT[idx] = f2bf(proj_w[(size_t)c * 320 + o]);
  }
  for (int idx = i0; idx < 400 * 320; idx += stride) {
    pwb[idx] = f2bf(pw_w[idx]);
  }
  for (int idx = i0; idx < 720 * 416; idx += stride) {
    const int o = idx / 416, c = idx - o * 416;
    float v = 0.f;
    if (c < 400) v = (o < 400) ? k_w[(size_t)c * 400 + o] : v_w[(size_t)c * 320 + (o - 400)];
    kvwT[idx] = f2bf(v);
  }
}

// ---------------------------------------------------------------------------
// Kernel 1a: depthwise 4x4/s4 conv, pure streaming; each x element is read by
// exactly one thread, so we ALSO emit the bf16 cast of x:
//   xbf  = bf16 x, overlaid in the qb region (row stride 400, cols 0..319)
//   dwc16 = bf16 dw-conv output, overlaid in the xs region (stride 416)
// grid 1960 (= 6272*80/256), thread = 4 channels of one output pixel.
// ---------------------------------------------------------------------------
__global__ __launch_bounds__(256) void k_dw(const float* __restrict__ x,
                                            const float* __restrict__ dw_w,
                                            const float* __restrict__ dw_b,
                                            u16* __restrict__ dwc16,
                                            u16* __restrict__ xbf) {
  const int idx = blockIdx.x * 256 + threadIdx.x;  // 6272*80
  const int row = idx / 80, c4 = (idx - row * 80) * 4;
  const int b = row / 196, pl = row - b * 196;
  const int oh = pl / 14, ow = pl - oh * 14;
  const size_t pix0 = (size_t)b * NN + (size_t)(oh * 4) * 56 + ow * 4;
  const float* xb = x + pix0 * CD + c4;

  float w[4][16];
#pragma unroll
  for (int k = 0; k < 4; k++)
#pragma unroll
    for (int j4 = 0; j4 < 4; j4++)
      *(float4*)&w[k][j4 * 4] = *(const float4*)(dw_w + (c4 + k) * 16 + j4 * 4);

  float a0 = dw_b[c4], a1 = dw_b[c4 + 1], a2 = dw_b[c4 + 2], a3 = dw_b[c4 + 3];
#pragma unroll
  for (int i = 0; i < 4; i++)
#pragma unroll
    for (int j = 0; j < 4; j++) {
      const float4 xv = *(const float4*)(xb + (size_t)(i * 56 + j) * CD);
      const int t = i * 4 + j;
      a0 += xv.x * w[0][t];
      a1 += xv.y * w[1][t];
      a2 += xv.z * w[2][t];
      a3 += xv.w * w[3][t];
      *(uint2*)(xbf + (pix0 + i * 56 + j) * CN + c4) =
          pack4(xv.x, xv.y, xv.z, xv.w);
    }
  *(uint2*)(dwc16 + (size_t)row * 416 + c4) = pack4(a0, a1, a2, a3);
}

// ---------------------------------------------------------------------------
// Kernel 1b v2: 1x1 conv + LN + GELU, N-SPLIT across 4 waves.
// Block = 256 thr, all 4 waves share the 16 rows (row0 = bx*16); wave wv owns
// n-tiles wv+4j. LN stats: per-wave partial -> 512B LDS -> one barrier.
// In-place in xs: reads dwc16 (cols 0..319), writes cols 0..399.
// ---------------------------------------------------------------------------
__global__ __launch_bounds__(256) void k_pwln(u16* xs,
                                              const u16* __restrict__ pwb,
                                              const float* __restrict__ pw_b,
                                              const float* __restrict__ ln_g,
                                              const float* __restrict__ ln_b) {
  __shared__ float redS[4][16], redQ[4][16];
  const int tid = threadIdx.x, lane = tid & 63, wv = tid >> 6;
  const int quad = lane >> 4, l15 = lane & 15;
  const int row0 = blockIdx.x * 16;
  const f32x4 fz = {0.f, 0.f, 0.f, 0.f};

  bf16x8 Bfr[10];
  {
    const u16* xr = xs + (size_t)(row0 + l15) * 416;
#pragma unroll
    for (int ks = 0; ks < 10; ks++)
      Bfr[ks] = *(const bf16x8*)(xr + ks * 32 + quad * 8);
  }
  f32x4 acc[7];
#pragma unroll
  for (int j = 0; j < 7; j++) acc[j] = fz;
#pragma unroll
  for (int j = 0; j < 7; j++) {
    const int n = wv + 4 * j;
    if (n < 25) {
      const u16* wr = pwb + (size_t)(n * 16 + l15) * CD;
#pragma unroll
      for (int ks = 0; ks < 10; ks++) {
        const bf16x8 A = *(const bf16x8*)(wr + ks * 32 + quad * 8);
        acc[j] = __builtin_amdgcn_mfma_f32_16x16x32_bf16(A, Bfr[ks], acc[j], 0, 0, 0);
      }
      const float4 pb = *(const float4*)(pw_b + n * 16 + quad * 4);
      acc[j][0] += pb.x; acc[j][1] += pb.y; acc[j][2] += pb.z; acc[j][3] += pb.w;
    }
  }
  // per-wave partial LN stats for row l15 (unused acc[] stay zero: harmless)
  float s = 0.f, ss = 0.f;
#pragma unroll
  for (int j = 0; j < 7; j++)
#pragma unroll
    for (int r = 0; r < 4; r++) {
      s += acc[j][r];
      ss += acc[j][r] * acc[j][r];
    }
  s += __shfl_xor(s, 16); ss += __shfl_xor(ss, 16);
  s += __shfl_xor(s, 32); ss += __shfl_xor(ss, 32);
  if (lane < 16) {
    redS[wv][l15] = s;
    redQ[wv][l15] = ss;
  }
  __syncthreads();
  s = redS[0][l15] + redS[1][l15] + redS[2][l15] + redS[3][l15];
  ss = redQ[0][l15] + redQ[1][l15] + redQ[2][l15] + redQ[3][l15];
  const float mu = s * (1.f / 400.f);
  const float var = ss * (1.f / 400.f) - mu * mu;
  const float rstd = rsqrtf(var + 1e-5f);

  u16* orow = xs + (size_t)(row0 + l15) * 416;
#pragma unroll
  for (int j = 0; j < 7; j++) {
    const int n = wv + 4 * j;
    if (n < 25) {
      const float4 g = *(const float4*)(ln_g + n * 16 + quad * 4);
      const float4 bb = *(const float4*)(ln_b + n * 16 + quad * 4);
      float ge[4];
#pragma unroll
      for (int r = 0; r < 4; r++) {
        const float gg = (&g.x)[r], bv = (&bb.x)[r];
        const float v = (acc[j][r] - mu) * rstd * gg + bv;
        ge[r] = 0.5f * v * (1.f + erff(v * 0.70710678118654752f));
      }
      *(uint2*)(orow + n * 16 + quad * 4) = pack4(ge[0], ge[1], ge[2], ge[3]);
    }
  }
  if (wv == 3) *(uint2*)(orow + 400 + quad * 4) = make_uint2(0, 0);
}

// ---------------------------------------------------------------------------
// Kernel 2 v2 (MFMA, LDS weight staging): xs @ kvwT^T -> kb / vt.
// grid (98, 9), 4 waves x 16 rows; nt-range = by*5..+5; kvwT n-tile [16][416]
// double-buffered in LDS in fragment order; one barrier per iter.
// ---------------------------------------------------------------------------
__global__ __launch_bounds__(256) void k_kv(const u16* __restrict__ xs,
                                            const u16* __restrict__ kvwT,
                                            u16* __restrict__ kb,
                                            u16* __restrict__ vt) {
  __shared__ u16 wlds[2][6656];  // 2 x 13312 B
  const int tid = threadIdx.x, lane = tid & 63, wv = tid >> 6;
  const int quad = lane >> 4, l15 = lane & 15;
  const int mt = blockIdx.x * 4 + wv;  // 0..391
  const int nt0 = blockIdx.y * 5;      // 0,5,...,40
  const f32x4 fz = {0.f, 0.f, 0.f, 0.f};

  bf16x8 A[13];
  {
    const u16* xr = xs + (size_t)(mt * 16 + l15) * 416;
#pragma unroll
    for (int ks = 0; ks < 13; ks++)
      A[ks] = *(const bf16x8*)(xr + ks * 32 + quad * 8);
  }

  for (int idx = tid; idx < 832; idx += 256) {
    const int ks = idx >> 6, ln = idx & 63, q = ln >> 4, l = ln & 15;
    *(uint4*)(wlds[0] + idx * 8) = *(const uint4*)(
        kvwT + (size_t)(nt0 * 16 + l) * 416 + ks * 32 + q * 8);
  }
  __syncthreads();

#pragma unroll 1
  for (int j = 0; j < 5; j++) {
    const int nt = nt0 + j;
    const u16* wb = wlds[j & 1];
    uint4 st0, st1, st2, st3;
    const bool t4 = tid < 64;
    if (j < 4) {
      const int base = (nt + 1) * 16;
      {
        const int idx = tid;
        const int ks = idx >> 6, ln = idx & 63, q = ln >> 4, l = ln & 15;
        st0 = *(const uint4*)(kvwT + (size_t)(base + l) * 416 + ks * 32 + q * 8);
      }
      {
        const int idx = tid + 256;
        const int ks = idx >> 6, ln = idx & 63, q = ln >> 4, l = ln & 15;
        st1 = *(const uint4*)(kvwT + (size_t)(base + l) * 416 + ks * 32 + q * 8);
      }
      {
        const int idx = tid + 512;
        const int ks = idx >> 6, ln = idx & 63, q = ln >> 4, l = ln & 15;
        st2 = *(const uint4*)(kvwT + (size_t)(base + l) * 416 + ks * 32 + q * 8);
      }
      if (t4) {
        const int idx = tid + 768;
        const int ks = idx >> 6, ln = idx & 63, q = ln >> 4, l = ln & 15;
        st3 = *(const uint4*)(kvwT + (size_t)(base + l) * 416 + ks * 32 + q * 8);
      }
    }
    f32x4 acc = fz;
#pragma unroll
    for (int ks = 0; ks < 13; ks++) {
      const bf16x8 B = *(const bf16x8*)(wb + ks * 512 + lane * 8);
      acc = __builtin_amdgcn_mfma_f32_16x16x32_bf16(A[ks], B, acc, 0, 0, 0);
    }
    const int col = nt * 16 + l15;
    if (col < 400) {
#pragma unroll
      for (int r = 0; r < 4; r++)
        kb[(size_t)(mt * 16 + quad * 4 + r) * 400 + col] = f2bf(acc[r]);
    } else {
      const int vo = col - 400;
#pragma unroll
      for (int r = 0; r < 4; r++) {
        const int row = mt * 16 + quad * 4 + r;
        const int bb = row / 196, key = row - bb * 196;
        vt[((size_t)(bb * 320 + vo)) * 224 + key] = f2bf(acc[r]);
      }
    }
    if (j < 4) {
      u16* wn = wlds[(j + 1) & 1];
      *(uint4*)(wn + tid * 8) = st0;
      *(uint4*)(wn + (tid + 256) * 8) = st1;
      *(uint4*)(wn + (tid + 512) * 8) = st2;
      if (t4) *(uint4*)(wn + (tid + 768) * 8) = st3;
      __syncthreads();
    }
  }
}

// ---------------------------------------------------------------------------
// Kernel 3 v3 (MFMA, OPERAND-SWAPPED, IN-PLACE, LDS weight staging):
// qb = x @ q_w. Block = 4 waves x 32 rows = 128 rows, grid 784.
// ---------------------------------------------------------------------------
__global__ __launch_bounds__(256) void k_q(u16* qb,
                                           const u16* __restrict__ qwT) {
  __shared__ u16 wlds[2][5120];  // 2 x 10240 B
  const int tid = threadIdx.x, lane = tid & 63;
  const int wv = tid >> 6, quad = lane >> 4, l15 = lane & 15;
  const int r0 = blockIdx.x * 128 + wv * 32;
  const f32x4 fz = {0.f, 0.f, 0.f, 0.f};

  bf16x8 Bfr[2][10];
#pragma unroll
  for (int t = 0; t < 2; t++) {
    const u16* xr = qb + (size_t)(r0 + t * 16 + l15) * CN;
#pragma unroll
    for (int ks = 0; ks < 10; ks++)
      Bfr[t][ks] = *(const bf16x8*)(xr + ks * 32 + quad * 8);
  }

  for (int idx = tid; idx < 640; idx += 256)
    *(uint4*)(wlds[0] + idx * 8) = *(const uint4*)(
        qwT + (size_t)(idx & 15) * CD + (idx >> 6) * 32 + ((idx >> 4) & 3) * 8);
  __syncthreads();

#pragma unroll 1
  for (int n = 0; n < 25; n++) {
    const u16* wb = wlds[n & 1];
    uint4 st0, st1, st2;
    const bool h2 = tid < 128;
    if (n < 24) {
      const int base = (n + 1) * 16;
      {
        const int idx = tid;
        st0 = *(const uint4*)(qwT + (size_t)(base + (idx & 15)) * CD +
                              (idx >> 6) * 32 + ((idx >> 4) & 3) * 8);
      }
      {
        const int idx = tid + 256;
        st1 = *(const uint4*)(qwT + (size_t)(base + (idx & 15)) * CD +
                              (idx >> 6) * 32 + ((idx >> 4) & 3) * 8);
      }
      if (h2) {
        const int idx = tid + 512;
        st2 = *(const uint4*)(qwT + (size_t)(base + (idx & 15)) * CD +
                              (idx >> 6) * 32 + ((idx >> 4) & 3) * 8);
      }
    }
    f32x4 acc[2] = {fz, fz};
#pragma unroll
    for (int ks = 0; ks < 10; ks++) {
      const bf16x8 A = *(const bf16x8*)(wb + ks * 512 + lane * 8);
      acc[0] = __builtin_amdgcn_mfma_f32_16x16x32_bf16(A, Bfr[0][ks], acc[0], 0, 0, 0);
      acc[1] = __builtin_amdgcn_mfma_f32_16x16x32_bf16(A, Bfr[1][ks], acc[1], 0, 0, 0);
    }
#pragma unroll
    for (int t = 0; t < 2; t++)
      *(uint2*)(qb + (size_t)(r0 + t * 16 + l15) * CN + n * 16 + quad * 4) =
          pack4(acc[t][0], acc[t][1], acc[t][2], acc[t][3]);
    if (n < 24) {
      u16* wn = wlds[(n + 1) & 1];
      *(uint4*)(wn + tid * 8) = st0;
      *(uint4*)(wn + (tid + 256) * 8) = st1;
      if (h2) *(uint4*)(wn + (tid + 512) * 8) = st2;
      __syncthreads();
    }
  }
}

// ---------------------------------------------------------------------------
// Kernel 4 v3: attention, OPERAND-SWAPPED, single barrier, P in registers.
// grid (5, 49, 32), 256 threads, LDS 31360 B -> 5 blocks/CU.
// Round-9 softmax surgery (VALU was 44.6% busy — dominant pipe):
//  - sacc kept RAW; max over raw; p = exp2(fma(sacc, C, -mx*C)), C=SCALE*log2e
//  - 4-way parallel max/sum accumulators (dep chain 52 -> 13+2)
//  - P packed UNNORMALIZED via v_cvt_pk_bf16_f32 (HW RNE, 1 op per 2 values)
//  - normalization deferred to oacc (inv is lane-local since col=l15=q-row)
// ---------------------------------------------------------------------------
__global__ __launch_bounds__(256, 5) void k_attn(u16* __restrict__ qb,
                                                 const u16* __restrict__ kb,
                                                 const u16* __restrict__ vt) {
  const int h = blockIdx.x, qt = blockIdx.y, b = blockIdx.z;
  const int tid = threadIdx.x, lane = tid & 63, wv = tid >> 6;
  const int quad = lane >> 4, l15 = lane & 15;
  const int q0 = qt * 64, m0 = wv * 16;
  const f32x4 fz = {0.f, 0.f, 0.f, 0.f};

  __shared__ u16 Ks[196 * 80];  // 31360 B

  // stage K head-slice [196][80] -> Ks, linear (dest byte = idx*16)
  for (int idx = tid; idx < 1960; idx += 256) {
    const int key = idx / 10, g = idx - key * 10;
    *(uint4*)(Ks + idx * 8) =
        *(const uint4*)(kb + ((size_t)(b * NKEY + key)) * CN + h * DQ + g * 8);
  }
  __syncthreads();  // the only barrier

  // ---- S^T (13 key-tiles; K=80 exact, zero-padded to 96 on both operands)
  f32x4 sacc[13];
#pragma unroll
  for (int n = 0; n < 13; n++) sacc[n] = fz;
  {
    union { uint4 u; bf16x8 v; } z;
    z.u = make_uint4(0, 0, 0, 0);
    const u16* qr = qb + (size_t)(b * NN + q0 + m0 + l15) * CN + h * DQ;
    bf16x8 bq0 = *(const bf16x8*)(qr + quad * 8);
    bf16x8 bq1 = *(const bf16x8*)(qr + 32 + quad * 8);
    bf16x8 bq2 = (quad < 2) ? *(const bf16x8*)(qr + 64 + quad * 8) : z.v;
#pragma unroll
    for (int n = 0; n < 13; n++) {
      const int rr = n * 16 + l15;
      const u16* kr = Ks + ((rr > 195) ? 195 : rr) * 80;
      sacc[n] = __builtin_amdgcn_mfma_f32_16x16x32_bf16(
          *(const bf16x8*)(kr + quad * 8), bq0, sacc[n], 0, 0, 0);
      sacc[n] = __builtin_amdgcn_mfma_f32_16x16x32_bf16(
          *(const bf16x8*)(kr + 32 + quad * 8), bq1, sacc[n], 0, 0, 0);
      const bf16x8 ak2 = (quad < 2) ? *(const bf16x8*)(kr + 64 + quad * 8) : z.v;
      sacc[n] = __builtin_amdgcn_mfma_f32_16x16x32_bf16(ak2, bq2, sacc[n], 0, 0, 0);
    }
  }

  // ---- softmax v3: raw max (4-way tree), fused fma+exp2, unnormalized pack
  u32 u[13][2];
  float inv;
  {
    // mask invalid keys 196..207 (n=12, quad!=0) in-place
    if (quad != 0) {
      sacc[12][0] = -1e30f; sacc[12][1] = -1e30f;
      sacc[12][2] = -1e30f; sacc[12][3] = -1e30f;
    }
    float m0r = -1e30f, m1r = -1e30f, m2r = -1e30f, m3r = -1e30f;
#pragma unroll
    for (int n = 0; n < 13; n++) {
      m0r = fmaxf(m0r, sacc[n][0]);
      m1r = fmaxf(m1r, sacc[n][1]);
      m2r = fmaxf(m2r, sacc[n][2]);
      m3r = fmaxf(m3r, sacc[n][3]);
    }
    float mx = fmaxf(fmaxf(m0r, m1r), fmaxf(m2r, m3r));
    mx = fmaxf(mx, __shfl_xor(mx, 16));
    mx = fmaxf(mx, __shfl_xor(mx, 32));
    const float C = SCALE_F * 1.4426950408889634f;  // SCALE * log2(e)
    const float mc = mx * C;
    float s0 = 0.f, s1 = 0.f, s2 = 0.f, s3 = 0.f;
#pragma unroll
    for (int n = 0; n < 13; n++) {
      const float p0 = EXP2F(__builtin_fmaf(sacc[n][0], C, -mc));
      const float p1 = EXP2F(__builtin_fmaf(sacc[n][1], C, -mc));
      const float p2 = EXP2F(__builtin_fmaf(sacc[n][2], C, -mc));
      const float p3 = EXP2F(__builtin_fmaf(sacc[n][3], C, -mc));
      s0 += p0; s1 += p1; s2 += p2; s3 += p3;
      u[n][0] = cvtpk(p0, p1);
      u[n][1] = cvtpk(p2, p3);
    }
    float sum = (s0 + s1) + (s2 + s3);
    sum += __shfl_xor(sum, 16);
    sum += __shfl_xor(sum, 32);
    inv = 1.f / sum;
  }

  // ---- O^T = P^T-fed MFMA; B-frags built by cross-quad shuffles
  f32x4 oacc[4];
#pragma unroll
  for (int nn = 0; nn < 4; nn++) oacc[nn] = fz;
  {
    const u16* vbase = vt + (size_t)(b * 320 + h * DV) * 224;
    const int src0 = ((lane & 16) << 1) | l15;  // (quad&1)*32 + l15
    const int src1 = src0 + 16;
    const bool hi = (quad >= 2);
#pragma unroll
    for (int kk = 0; kk < 7; kk++) {
      union { bf16x8 v; u32 w[4]; } bp;
      const u32 a0 = (u32)__shfl((int)u[2 * kk][0], src0);
      const u32 a1 = (u32)__shfl((int)u[2 * kk][1], src0);
      const u32 a2 = (u32)__shfl((int)u[2 * kk][0], src1);
      const u32 a3 = (u32)__shfl((int)u[2 * kk][1], src1);
      u32 b0 = 0, b1 = 0, b2 = 0, b3 = 0;
      if (kk < 6) {
        b0 = (u32)__shfl((int)u[2 * kk + 1][0], src0);
        b1 = (u32)__shfl((int)u[2 * kk + 1][1], src0);
        b2 = (u32)__shfl((int)u[2 * kk + 1][0], src1);
        b3 = (u32)__shfl((int)u[2 * kk + 1][1], src1);
      }
      bp.w[0] = hi ? b0 : a0;
      bp.w[1] = hi ? b1 : a1;
      bp.w[2] = hi ? b2 : a2;
      bp.w[3] = hi ? b3 : a3;
#pragma unroll
      for (int nn = 0; nn < 4; nn++) {
        const bf16x8 A = *(const bf16x8*)(vbase + (size_t)(nn * 16 + l15) * 224 +
                                          kk * 32 + quad * 8);
        oacc[nn] = __builtin_amdgcn_mfma_f32_16x16x32_bf16(A, bp.v, oacc[nn], 0, 0, 0);
      }
    }
  }
  // ---- normalize (deferred) + bf16 attn-out overlay into qb
  u16* orow = qb + (size_t)(b * NN + q0 + m0 + l15) * CN + h * DQ;
#pragma unroll
  for (int nn = 0; nn < 4; nn++)
    *(uint2*)(orow + nn * 16 + quad * 4) =
        make_uint2(cvtpk(oacc[nn][0] * inv, oacc[nn][1] * inv),
                   cvtpk(oacc[nn][2] * inv, oacc[nn][3] * inv));
}

// ---------------------------------------------------------------------------
// Kernel 5 v3 (OPERAND-SWAPPED, LDS weight staging): out = ao @ proj_w + b.
// Block = 4 waves x 32 rows, grid 784; pwT n-tile double-buffered in LDS.
// ---------------------------------------------------------------------------
__global__ __launch_bounds__(256) void k_proj(const u16* __restrict__ ao,
                                              const u16* __restrict__ pwT,
                                              const float* __restrict__ proj_b,
                                              float* __restrict__ out) {
  __shared__ u16 wlds[2][5120];  // 2 x 10240 B
  const int tid = threadIdx.x, lane = tid & 63;
  const int wv = tid >> 6, quad = lane >> 4, l15 = lane & 15;
  const int r0 = blockIdx.x * 128 + wv * 32;
  const f32x4 fz = {0.f, 0.f, 0.f, 0.f};

  bf16x8 Bfr[2][10];
#pragma unroll
  for (int t = 0; t < 2; t++) {
    const u16* xr = ao + (size_t)(r0 + t * 16 + l15) * CN;
#pragma unroll
    for (int ks = 0; ks < 10; ks++)
      Bfr[t][ks] = *(const bf16x8*)(xr + (ks >> 1) * DQ + (ks & 1) * 32 + quad * 8);
  }

  for (int idx = tid; idx < 640; idx += 256)
    *(uint4*)(wlds[0] + idx * 8) = *(const uint4*)(
        pwT + (size_t)(idx & 15) * CD + (idx >> 6) * 32 + ((idx >> 4) & 3) * 8);
  __syncthreads();

#pragma unroll 1
  for (int n = 0; n < 20; n++) {
    const u16* wb = wlds[n & 1];
    uint4 st0, st1, st2;
    const bool h2 = tid < 128;
    if (n < 19) {
      const int base = (n + 1) * 16;
      {
        const int idx = tid;
        st0 = *(const uint4*)(pwT + (size_t)(base + (idx & 15)) * CD +
                              (idx >> 6) * 32 + ((idx >> 4) & 3) * 8);
      }
      {
        const int idx = tid + 256;
        st1 = *(const uint4*)(pwT + (size_t)(base + (idx & 15)) * CD +
                              (idx >> 6) * 32 + ((idx >> 4) & 3) * 8);
      }
      if (h2) {
        const int idx = tid + 512;
        st2 = *(const uint4*)(pwT + (size_t)(base + (idx & 15)) * CD +
                              (idx >> 6) * 32 + ((idx >> 4) & 3) * 8);
      }
    }
    f32x4 acc[2] = {fz, fz};
#pragma unroll
    for (int ks = 0; ks < 10; ks++) {
      const bf16x8 A = *(const bf16x8*)(wb + ks * 512 + lane * 8);
      acc[0] = __builtin_amdgcn_mfma_f32_16x16x32_bf16(A, Bfr[0][ks], acc[0], 0, 0, 0);
      acc[1] = __builtin_amdgcn_mfma_f32_16x16x32_bf16(A, Bfr[1][ks], acc[1], 0, 0, 0);
    }
    const float4 pb = *(const float4*)(proj_b + n * 16 + quad * 4);
#pragma unroll
    for (int t = 0; t < 2; t++) {
      float4 o;
      o.x = acc[t][0] + pb.x;
      o.y = acc[t][1] + pb.y;
      o.z = acc[t][2] + pb.z;
      o.w = acc[t][3] + pb.w;
      *(float4*)(out + (size_t)(r0 + t * 16 + l15) * CD + n * 16 + quad * 4) = o;
    }
    if (n < 19) {
      u16* wn = wlds[(n + 1) & 1];
      *(uint4*)(wn + tid * 8) = st0;
      *(uint4*)(wn + (tid + 256) * 8) = st1;
      if (h2) *(uint4*)(wn + (tid + 512) * 8) = st2;
      __syncthreads();
    }
  }
}

// ---------------------------------------------------------------------------
extern "C" void kernel_launch(void* const* d_in, const int* in_sizes, int n_in,
                              void* d_out, int out_size, void* d_ws,
                              size_t ws_size, hipStream_t stream) {
  const float* x = (const float*)d_in[0];
  const float* dw_w = (const float*)d_in[3];
  const float* dw_b = (const float*)d_in[4];
  const float* pw_w = (const float*)d_in[5];
  const float* pw_b = (const float*)d_in[6];
  const float* ln_g = (const float*)d_in[7];
  const float* ln_b = (const float*)d_in[8];
  const float* q_w = (const float*)d_in[9];
  const float* k_w = (const float*)d_in[10];
  const float* v_w = (const float*)d_in[11];
  const float* proj_w = (const float*)d_in[12];
  const float* proj_b = (const float*)d_in[13];
  float* out = (float*)d_out;

  u16* w = (u16*)d_ws;
  u16* xs16 = w;                    // [6272][416]       = 2,609,152  (hosts dwc16 overlay)
  u16* kb16 = xs16 + 2609152;       // [6272][400]       = 2,508,800
  u16* vt16 = kb16 + 2508800;       // [32*320][224]     = 2,293,760
  u16* qb16 = vt16 + 2293760;       // [100352][400]+64  = 40,140,864 (hosts xbf + ao overlays)
  u16* qwT = qb16 + 40140864;       // [400][320]        = 128,000
  u16* pwT = qwT + 128000;          // [320][320]        = 102,400
  u16* kvwT = pwT + 102400;         // [720][416]        = 299,520
  u16* pwb = kvwT + 299520;         // [400][320]        = 128,000
                                    // total ~96.5 MB

  k_prep<<<512, 256, 0, stream>>>(q_w, proj_w, k_w, v_w, pw_w, qwT, pwT, kvwT,
                                  pwb);
  k_dw<<<1960, 256, 0, stream>>>(x, dw_w, dw_b, xs16 /*dwc16 overlay*/,
                                 qb16 /*xbf overlay*/);
  k_pwln<<<392, 256, 0, stream>>>(xs16, pwb, pw_b, ln_g, ln_b);
  k_kv<<<dim3(98, 9), 256, 0, stream>>>(xs16, kvwT, kb16, vt16);
  k_q<<<784, 256, 0, stream>>>(qb16, qwT);
  k_attn<<<dim3(NH, 49, NB), 256, 0, stream>>>(qb16, kb16, vt16);
  k_proj<<<784, 256, 0, stream>>>(qb16, pwT, proj_b, out);
}